// Round 6
// baseline (538.014 us; speedup 1.0000x reference)
//
#include <hip/hip_runtime.h>
#include <hip/hip_bf16.h>

#define NSRC 65536
#define NDST 8192
#define H 128

// mixing constants: z2sim = 0.34*sim + 0.495*cor@Wcs + 0.165*sim@(Wsc@Wcs) (and sym.)
#define C_SELF 0.34f
#define C_CROSS 0.495f
#define C_DBL  0.165f

typedef float f32x16 __attribute__((ext_vector_type(16)));

static __device__ __forceinline__ float b2f(unsigned short u) {
  union { unsigned int i; float f; } v; v.i = ((unsigned int)u) << 16; return v.f;
}
static __device__ __forceinline__ unsigned short f2b(float f) {
  union { float f; unsigned int i; } v; v.f = f;
  unsigned int x = v.i;
  return (unsigned short)((x + 0x7fffu + ((x >> 16) & 1u)) >> 16);  // RNE
}
static __device__ __forceinline__ void load4bf(const unsigned short* p, float* d) {
  ushort4 u = *(const ushort4*)p;
  d[0] = b2f(u.x); d[1] = b2f(u.y); d[2] = b2f(u.z); d[3] = b2f(u.w);
}
static __device__ __forceinline__ void store4bf(unsigned short* p, const float* d) {
  ushort4 u; u.x = f2b(d[0]); u.y = f2b(d[1]); u.z = f2b(d[2]); u.w = f2b(d[3]);
  *(ushort4*)p = u;
}
// fp8 e4m3fn (OCP) -> f32, branchless-ish manual decode (handles subnormals).
static __device__ __forceinline__ float fp8_to_f32(unsigned int b) {
  const unsigned e = (b >> 3) & 15u, m = b & 7u;
  union { unsigned i; float f; } v; v.i = ((e + 120u) << 23) | (m << 20);
  float f = (e == 0u) ? (float)m * 1.953125e-3f : v.f;   // subnormal: m * 2^-9
  return (b & 0x80u) ? -f : f;
}
// dual-dtype loaders: f32flag=1 -> buffer holds float32, else bf16.
static __device__ __forceinline__ void load4any(const void* base, size_t idx, int f32flag, float* d) {
  if (f32flag) {
    float4 v = *(const float4*)((const float*)base + idx);
    d[0] = v.x; d[1] = v.y; d[2] = v.z; d[3] = v.w;
  } else {
    load4bf((const unsigned short*)base + idx, d);
  }
}
static __device__ __forceinline__ float load1any(const void* base, size_t idx, int f32flag) {
  return f32flag ? ((const float*)base)[idx] : b2f(((const unsigned short*)base)[idx]);
}

// flags[0]=1 iff float tensors are f32 (else bf16). flags[1]=1 iff x is int64 (else int32).
__global__ void detect(const unsigned short* __restrict__ W, const int* __restrict__ x,
                       int* __restrict__ flags) {
  if (threadIdx.x != 0 || blockIdx.x != 0) return;
  int bad = 0;
  for (int i = 0; i < 128; ++i) {
    unsigned short u = W[i];
    if (u != 0) {
      int e = (u >> 7) & 0xFF;
      if (e < 90 || e > 128) bad++;
    }
  }
  flags[0] = (bad > 8) ? 1 : 0;
  int allz = 1;
  for (int r = 0; r < 16; ++r)
    if (x[2 * r + 1] != 0) allz = 0;
  flags[1] = allz;
}

// feat[r,:] = [emb0[x0[r]] | emb1[x1[r]]] @ W + b   (65536 x 128, K=128)
// Writes fp8 table (full, for coatt gather) + bf16 table (first NDST rows only, h_self).
__global__ __launch_bounds__(256) void featgemm(
    const int* __restrict__ x,
    const void* __restrict__ emb0,
    const void* __restrict__ emb1,
    const void* __restrict__ W,
    const void* __restrict__ bvec,
    const int* __restrict__ flags,
    unsigned char* __restrict__ feat8,
    unsigned short* __restrict__ feat16)
{
  const int wf  = flags[0];
  const int x64 = flags[1];
  const int t = threadIdx.x;
  const int rt = t >> 5, ct = t & 31;
  const int r0 = blockIdx.x * 32 + rt * 4;
  const int c0 = ct * 4;

  float acc[4][4];
  float bv[4]; load4any(bvec, c0, wf, bv);
#pragma unroll
  for (int i = 0; i < 4; ++i)
#pragma unroll
    for (int j = 0; j < 4; ++j) acc[i][j] = bv[j];

  int x0[4], x1[4];
#pragma unroll
  for (int i = 0; i < 4; ++i) {
    if (x64) { x0[i] = x[(r0 + i) * 4]; x1[i] = x[(r0 + i) * 4 + 2]; }
    else     { x0[i] = x[(r0 + i) * 2]; x1[i] = x[(r0 + i) * 2 + 1]; }
  }

  float a[4][4], w[4];
  for (int k = 0; k < 32; k += 4) {
#pragma unroll
    for (int i = 0; i < 4; ++i) load4any(emb0, (size_t)x0[i] * 32 + k, wf, a[i]);
#pragma unroll
    for (int kk = 0; kk < 4; ++kk) {
      load4any(W, (size_t)(k + kk) * H + c0, wf, w);
#pragma unroll
      for (int i = 0; i < 4; ++i) {
        const float av = a[i][kk];
#pragma unroll
        for (int j = 0; j < 4; ++j) acc[i][j] += av * w[j];
      }
    }
  }
  for (int k = 32; k < 128; k += 4) {
#pragma unroll
    for (int i = 0; i < 4; ++i) load4any(emb1, (size_t)x1[i] * 96 + (k - 32), wf, a[i]);
#pragma unroll
    for (int kk = 0; kk < 4; ++kk) {
      load4any(W, (size_t)(k + kk) * H + c0, wf, w);
#pragma unroll
      for (int i = 0; i < 4; ++i) {
        const float av = a[i][kk];
#pragma unroll
        for (int j = 0; j < 4; ++j) acc[i][j] += av * w[j];
      }
    }
  }
#pragma unroll
  for (int i = 0; i < 4; ++i) {
    const int row = r0 + i;
    // pack 4 fp8 bytes (HW cvt, RNE): bytes 0,1 then 2,3
    int p = __builtin_amdgcn_cvt_pk_fp8_f32(acc[i][0], acc[i][1], 0, false);
    p = __builtin_amdgcn_cvt_pk_fp8_f32(acc[i][2], acc[i][3], p, true);
    *(int*)(feat8 + (size_t)row * H + c0) = p;
    if (row < NDST) store4bf(feat16 + (size_t)row * H + c0, acc[i]);
  }
}

// Collapsed co-attention pool, one WAVE per node. fp8 gather + fp8 MFMA for L = D.Q^T.
__global__ __launch_bounds__(256) void coatt_mfma(
    const unsigned char* __restrict__ feat8,
    const unsigned short* __restrict__ feat16,
    const int* __restrict__ idxD,
    const int* __restrict__ idxQ,
    unsigned short* __restrict__ rst)
{
  __shared__ float gbuf[4][416];   // per wave: g[384] | sv[32]
  const int t = threadIdx.x;
  const int w = t >> 6;            // wave in block
  const int l = t & 63;            // lane
  const int r = l & 31;            // row index within D/Q tiles
  const int half = l >> 5;
  const int n = blockIdx.x * 4 + w;

  float* g   = gbuf[w];
  float* svb = gbuf[w] + 384;

  const int gD = idxD[n * 32 + r];
  const int gQ = idxQ[n * 32 + r];
  const unsigned char* drow = feat8 + (size_t)gD * H + half * 8;
  const unsigned char* qrow = feat8 + (size_t)gQ * H + half * 8;

  // A/B fragments for v_mfma_f32_32x32x16_fp8_fp8 (8 fp8/lane = i64):
  // lane holds X[row=l&31][k=(l>>5)*8+j]. Both row-gathered => D.Q^T.
  long dfrag[8], qfrag[8];
#pragma unroll
  for (int s = 0; s < 8; ++s) {
    dfrag[s] = *(const long*)(drow + s * 16);
    qfrag[s] = *(const long*)(qrow + s * 16);
  }

  f32x16 acc = {0,0,0,0,0,0,0,0,0,0,0,0,0,0,0,0};
#pragma unroll
  for (int s = 0; s < 8; ++s)
    acc = __builtin_amdgcn_mfma_f32_32x32x16_fp8_fp8(dfrag[s], qfrag[s], acc, 0, 0, 0);
  // L[m][k]: col k = l&31, row m = (reg&3) + 8*(reg>>2) + 4*half (shape-determined layout)

  // ---- row softmax stats (AC: over k = across the 32 lanes of this half) ----
  float er[16], rrcp[16];
#pragma unroll
  for (int i = 0; i < 16; ++i) {
    float m = acc[i];
#pragma unroll
    for (int d = 1; d < 32; d <<= 1) m = fmaxf(m, __shfl_xor(m, d));
    er[i] = __expf(acc[i] - m);
    float s = er[i];
#pragma unroll
    for (int d = 1; d < 32; d <<= 1) s += __shfl_xor(s, d);
    rrcp[i] = 1.0f / s;
  }

  // ---- col softmax stats (AS: over m = 16 regs in-lane + partner lane l^32) ----
  float cmax = acc[0];
#pragma unroll
  for (int i = 1; i < 16; ++i) cmax = fmaxf(cmax, acc[i]);
  cmax = fmaxf(cmax, __shfl_xor(cmax, 32));
  float es[16], csum = 0.f;
#pragma unroll
  for (int i = 0; i < 16; ++i) { es[i] = __expf(acc[i] - cmax); csum += es[i]; }
  csum += __shfl_xor(csum, 32);
  const float crcp = 1.0f / csum;

  // sv[m] = sum_k AS[k,m]
  float svr[16];
#pragma unroll
  for (int i = 0; i < 16; ++i) {
    float s = es[i] * crcp;
#pragma unroll
    for (int d = 1; d < 32; d <<= 1) s += __shfl_xor(s, d);
    svr[i] = s;
  }
  // tv[k] = sum_m sv[m]*AC[m,k]
  float tvp = 0.f;
#pragma unroll
  for (int i = 0; i < 16; ++i) tvp += svr[i] * er[i] * rrcp[i];
  const float tv = tvp + __shfl_xor(tvp, 32);

  // stage sv -> LDS so each lane can fetch sv[its row r]
  if (r == 0) {
    *(float4*)(svb + 4 * half)      = make_float4(svr[0],  svr[1],  svr[2],  svr[3]);
    *(float4*)(svb + 8 + 4 * half)  = make_float4(svr[4],  svr[5],  svr[6],  svr[7]);
    *(float4*)(svb + 16 + 4 * half) = make_float4(svr[8],  svr[9],  svr[10], svr[11]);
    *(float4*)(svb + 24 + 4 * half) = make_float4(svr[12], svr[13], svr[14], svr[15]);
  }
  const float svl = svb[r];

  // ---- pooled components: g = [u | v | w], u=sum_r Q, v=sum_r sv*D, w=sum_r tv*Q ----
#pragma unroll
  for (int s = 0; s < 8; ++s) {
    const unsigned long long du = (unsigned long long)dfrag[s];
    const unsigned long long qu = (unsigned long long)qfrag[s];
    float uq[8], vd[8], wq[8];
#pragma unroll
    for (int j = 0; j < 8; ++j) {
      const float dv = fp8_to_f32((unsigned int)(du >> (8 * j)) & 0xFFu);
      const float qv = fp8_to_f32((unsigned int)(qu >> (8 * j)) & 0xFFu);
      uq[j] = qv; vd[j] = svl * dv; wq[j] = tv * qv;
    }
#pragma unroll
    for (int d = 1; d < 32; d <<= 1) {
#pragma unroll
      for (int j = 0; j < 8; ++j) {
        uq[j] += __shfl_xor(uq[j], d);
        vd[j] += __shfl_xor(vd[j], d);
        wq[j] += __shfl_xor(wq[j], d);
      }
    }
    if (r == 0) {
      const int hb = s * 16 + half * 8;
      *(float4*)(g + hb)           = make_float4(uq[0], uq[1], uq[2], uq[3]);
      *(float4*)(g + hb + 4)       = make_float4(uq[4], uq[5], uq[6], uq[7]);
      *(float4*)(g + 128 + hb)     = make_float4(vd[0], vd[1], vd[2], vd[3]);
      *(float4*)(g + 128 + hb + 4) = make_float4(vd[4], vd[5], vd[6], vd[7]);
      *(float4*)(g + 256 + hb)     = make_float4(wq[0], wq[1], wq[2], wq[3]);
      *(float4*)(g + 256 + hb + 4) = make_float4(wq[4], wq[5], wq[6], wq[7]);
    }
  }

  // pooled[h'] = (g[3h'] + g[3h'+1] + g[3h'+2]) / 96 ;  rst = h_self + pooled
#pragma unroll
  for (int rep = 0; rep < 2; ++rep) {
    const int hp = l + rep * 64;
    const float p = (g[3 * hp] + g[3 * hp + 1] + g[3 * hp + 2]) * (1.0f / 96.0f);
    const float hs = b2f(feat16[(size_t)n * H + hp]);
    rst[(size_t)n * H + hp] = f2b(hs + p);
  }
}

// P1 = Wo_s@Wsc, P2 = Wo_c@Wcs, p1 = b_s@Wsc, p2 = b_c@Wcs
__global__ __launch_bounds__(128) void smallmm1(
    const void* __restrict__ Wos, const void* __restrict__ Woc,
    const void* __restrict__ Wsc, const void* __restrict__ Wcs,
    const void* __restrict__ bs, const void* __restrict__ bc,
    const int* __restrict__ flags,
    float* __restrict__ P1, float* __restrict__ P2,
    float* __restrict__ p1, float* __restrict__ p2)
{
  const int wf = flags[0];
  const int bid = blockIdx.x, c = threadIdx.x;
  if (bid < 128) {
    const int r = bid; float acc = 0.f;
    for (int k = 0; k < 128; ++k) acc += load1any(Wos, r * 128 + k, wf) * load1any(Wsc, k * 128 + c, wf);
    P1[r * 128 + c] = acc;
  } else if (bid < 256) {
    const int r = bid - 128; float acc = 0.f;
    for (int k = 0; k < 128; ++k) acc += load1any(Woc, r * 128 + k, wf) * load1any(Wcs, k * 128 + c, wf);
    P2[r * 128 + c] = acc;
  } else if (bid == 256) {
    float acc = 0.f;
    for (int k = 0; k < 128; ++k) acc += load1any(bs, k, wf) * load1any(Wsc, k * 128 + c, wf);
    p1[c] = acc;
  } else {
    float acc = 0.f;
    for (int k = 0; k < 128; ++k) acc += load1any(bc, k, wf) * load1any(Wcs, k * 128 + c, wf);
    p2[c] = acc;
  }
}

// Mss = C_SELF*Wo_s + C_DBL*P1@Wcs ; Mcc = C_SELF*Wo_c + C_DBL*P2@Wsc ; fused biases
__global__ __launch_bounds__(128) void smallmm2(
    const void* __restrict__ Wos, const void* __restrict__ Woc,
    const void* __restrict__ Wsc, const void* __restrict__ Wcs,
    const void* __restrict__ bs, const void* __restrict__ bc,
    const int* __restrict__ flags,
    const float* __restrict__ P1, const float* __restrict__ P2,
    const float* __restrict__ p1, const float* __restrict__ p2,
    float* __restrict__ Mss, float* __restrict__ Mcc,
    float* __restrict__ bsim, float* __restrict__ bcor)
{
  const int wf = flags[0];
  const int bid = blockIdx.x, c = threadIdx.x;
  if (bid < 128) {
    const int r = bid; float acc = 0.f;
    for (int k = 0; k < 128; ++k) acc += P1[r * 128 + k] * load1any(Wcs, k * 128 + c, wf);
    Mss[r * 128 + c] = C_SELF * load1any(Wos, r * 128 + c, wf) + C_DBL * acc;
  } else if (bid < 256) {
    const int r = bid - 128; float acc = 0.f;
    for (int k = 0; k < 128; ++k) acc += P2[r * 128 + k] * load1any(Wsc, k * 128 + c, wf);
    Mcc[r * 128 + c] = C_SELF * load1any(Woc, r * 128 + c, wf) + C_DBL * acc;
  } else if (bid == 256) {
    float acc = 0.f;
    for (int k = 0; k < 128; ++k) acc += p1[k] * load1any(Wcs, k * 128 + c, wf);
    bsim[c] = C_SELF * load1any(bs, c, wf) + C_CROSS * p2[c] + C_DBL * acc;
  } else {
    float acc = 0.f;
    for (int k = 0; k < 128; ++k) acc += p2[k] * load1any(Wsc, k * 128 + c, wf);
    bcor[c] = C_SELF * load1any(bc, c, wf) + C_CROSS * p1[c] + C_DBL * acc;
  }
}

// z2sim = Rs@Mss + C_CROSS*(Rc@P2) + bsim ; z2cor = Rc@Mcc + C_CROSS*(Rs@P1) + bcor
// OUTPUT IS FLOAT32.
__global__ __launch_bounds__(256) void finalmm(
    const unsigned short* __restrict__ Rs, const unsigned short* __restrict__ Rc,
    const float* __restrict__ Mss, const float* __restrict__ Mcc,
    const float* __restrict__ P1, const float* __restrict__ P2,
    const float* __restrict__ bsim, const float* __restrict__ bcor,
    float* __restrict__ outp)
{
  const int t = threadIdx.x;
  const int rt = t >> 5, ct = t & 31;
  const int r0 = blockIdx.x * 32 + rt * 4;
  const int c0 = ct * 4;
  float sA[4][4] = {}, sB[4][4] = {}, cA[4][4] = {}, cB[4][4] = {};

  for (int k = 0; k < 128; k += 4) {
    float a_s[4][4], a_c[4][4];
#pragma unroll
    for (int i = 0; i < 4; ++i) {
      load4bf(Rs + (size_t)(r0 + i) * H + k, a_s[i]);
      load4bf(Rc + (size_t)(r0 + i) * H + k, a_c[i]);
    }
#pragma unroll
    for (int kk = 0; kk < 4; ++kk) {
      float4 mss = *(const float4*)(Mss + (size_t)(k + kk) * H + c0);
      float4 mcc = *(const float4*)(Mcc + (size_t)(k + kk) * H + c0);
      float4 pp1 = *(const float4*)(P1 + (size_t)(k + kk) * H + c0);
      float4 pp2 = *(const float4*)(P2 + (size_t)(k + kk) * H + c0);
#pragma unroll
      for (int i = 0; i < 4; ++i) {
        const float as = a_s[i][kk], ac = a_c[i][kk];
        sA[i][0] += as * mss.x; sA[i][1] += as * mss.y; sA[i][2] += as * mss.z; sA[i][3] += as * mss.w;
        cB[i][0] += as * pp1.x; cB[i][1] += as * pp1.y; cB[i][2] += as * pp1.z; cB[i][3] += as * pp1.w;
        sB[i][0] += ac * pp2.x; sB[i][1] += ac * pp2.y; sB[i][2] += ac * pp2.z; sB[i][3] += ac * pp2.w;
        cA[i][0] += ac * mcc.x; cA[i][1] += ac * mcc.y; cA[i][2] += ac * mcc.z; cA[i][3] += ac * mcc.w;
      }
    }
  }
  float4 bsv = *(const float4*)(bsim + c0);
  float4 bcv = *(const float4*)(bcor + c0);
#pragma unroll
  for (int i = 0; i < 4; ++i) {
    float4 o1, o2;
    o1.x = sA[i][0] + C_CROSS * sB[i][0] + bsv.x;
    o1.y = sA[i][1] + C_CROSS * sB[i][1] + bsv.y;
    o1.z = sA[i][2] + C_CROSS * sB[i][2] + bsv.z;
    o1.w = sA[i][3] + C_CROSS * sB[i][3] + bsv.w;
    *(float4*)(outp + (size_t)(r0 + i) * H + c0) = o1;
    o2.x = cA[i][0] + C_CROSS * cB[i][0] + bcv.x;
    o2.y = cA[i][1] + C_CROSS * cB[i][1] + bcv.y;
    o2.z = cA[i][2] + C_CROSS * cB[i][2] + bcv.z;
    o2.w = cA[i][3] + C_CROSS * cB[i][3] + bcv.w;
    *(float4*)(outp + (size_t)NDST * H + (size_t)(r0 + i) * H + c0) = o2;
  }
}

extern "C" void kernel_launch(void* const* d_in, const int* in_sizes, int n_in,
                              void* d_out, int out_size, void* d_ws, size_t ws_size,
                              hipStream_t stream) {
  const int* x    = (const int*)d_in[0];
  const int* nsim = (const int*)d_in[1];
  const int* ncor = (const int*)d_in[2];
  const void* emb0_sim = d_in[3];
  const void* emb1_sim = d_in[4];
  const void* emb0_cor = d_in[5];
  const void* emb1_cor = d_in[6];
  const void* W_in_sim  = d_in[7];
  const void* b_in_sim  = d_in[8];
  const void* W_in_cor  = d_in[9];
  const void* b_in_cor  = d_in[10];
  const void* W_out_sim = d_in[11];
  const void* b_out_sim = d_in[12];
  const void* W_out_cor = d_in[13];
  const void* b_out_cor = d_in[14];
  const void* W_sim2cor = d_in[15];
  const void* W_cor2sim = d_in[16];

  // layout: f32 smalls | flags | bf16 tables | rst | fp8 tables
  float* fbase = (float*)d_ws;
  float* P1  = fbase;                   // 128*128 each
  float* P2  = P1 + H * H;
  float* Mss = P2 + H * H;
  float* Mcc = Mss + H * H;
  float* p1v = Mcc + H * H;             // 128 each
  float* p2v = p1v + H;
  float* bsimv = p2v + H;
  float* bcorv = bsimv + H;
  int* flags = (int*)(bcorv + H);       // 4 ints
  unsigned short* feat16_sim = (unsigned short*)(flags + 4);     // NDST*H
  unsigned short* feat16_cor = feat16_sim + (size_t)NDST * H;
  unsigned short* rst_sim    = feat16_cor + (size_t)NDST * H;    // NDST*H
  unsigned short* rst_cor    = rst_sim + (size_t)NDST * H;
  unsigned char* feat8_sim = (unsigned char*)(rst_cor + (size_t)NDST * H);  // NSRC*H bytes
  unsigned char* feat8_cor = feat8_sim + (size_t)NSRC * H;

  detect<<<1, 64, 0, stream>>>((const unsigned short*)W_in_sim, x, flags);
  smallmm1<<<258, 128, 0, stream>>>(W_out_sim, W_out_cor, W_sim2cor, W_cor2sim,
                                    b_out_sim, b_out_cor, flags, P1, P2, p1v, p2v);
  smallmm2<<<258, 128, 0, stream>>>(W_out_sim, W_out_cor, W_sim2cor, W_cor2sim,
                                    b_out_sim, b_out_cor, flags, P1, P2, p1v, p2v,
                                    Mss, Mcc, bsimv, bcorv);
  featgemm<<<NSRC / 32, 256, 0, stream>>>(x, emb0_sim, emb1_sim, W_in_sim, b_in_sim, flags,
                                          feat8_sim, feat16_sim);
  featgemm<<<NSRC / 32, 256, 0, stream>>>(x, emb0_cor, emb1_cor, W_in_cor, b_in_cor, flags,
                                          feat8_cor, feat16_cor);
  // mode 'sim': D = feat[neigh_cor], Q = feat[neigh_sim]
  coatt_mfma<<<NDST / 4, 256, 0, stream>>>(feat8_sim, feat16_sim, ncor, nsim, rst_sim);
  // mode 'cor': D = feat[neigh_sim], Q = feat[neigh_cor]
  coatt_mfma<<<NDST / 4, 256, 0, stream>>>(feat8_cor, feat16_cor, nsim, ncor, rst_cor);
  finalmm<<<NDST / 32, 256, 0, stream>>>(rst_sim, rst_cor, Mss, Mcc, P1, P2,
                                         bsimv, bcorv, (float*)d_out);
}

// Round 7
// 390.141 us; speedup vs baseline: 1.3790x; 1.3790x over previous
//
#include <hip/hip_runtime.h>
#include <hip/hip_bf16.h>

#define NSRC 65536
#define NDST 8192
#define H 128

// mixing constants: z2sim = 0.34*sim + 0.495*cor@Wcs + 0.165*sim@(Wsc@Wcs) (and sym.)
#define C_SELF 0.34f
#define C_CROSS 0.495f
#define C_DBL  0.165f

typedef float f32x16 __attribute__((ext_vector_type(16)));

static __device__ __forceinline__ float b2f(unsigned short u) {
  union { unsigned int i; float f; } v; v.i = ((unsigned int)u) << 16; return v.f;
}
static __device__ __forceinline__ unsigned short f2b(float f) {
  union { float f; unsigned int i; } v; v.f = f;
  unsigned int x = v.i;
  return (unsigned short)((x + 0x7fffu + ((x >> 16) & 1u)) >> 16);  // RNE
}
static __device__ __forceinline__ void load4bf(const unsigned short* p, float* d) {
  ushort4 u = *(const ushort4*)p;
  d[0] = b2f(u.x); d[1] = b2f(u.y); d[2] = b2f(u.z); d[3] = b2f(u.w);
}
static __device__ __forceinline__ void store4bf(unsigned short* p, const float* d) {
  ushort4 u; u.x = f2b(d[0]); u.y = f2b(d[1]); u.z = f2b(d[2]); u.w = f2b(d[3]);
  *(ushort4*)p = u;
}
// fp8 e4m3 x4 -> f32 (HW cvt if available; else manual incl. subnormals)
static __device__ __forceinline__ float fp8_manual(unsigned int b) {
  const unsigned e = (b >> 3) & 15u, m = b & 7u;
  union { unsigned i; float f; } v; v.i = ((e + 120u) << 23) | (m << 20);
  float f = (e == 0u) ? (float)m * 1.953125e-3f : v.f;
  return (b & 0x80u) ? -f : f;
}
static __device__ __forceinline__ void fp8x4_to_f32(int w, float* out) {
#if __has_builtin(__builtin_amdgcn_cvt_f32_fp8)
  out[0] = __builtin_amdgcn_cvt_f32_fp8(w, 0);
  out[1] = __builtin_amdgcn_cvt_f32_fp8(w, 1);
  out[2] = __builtin_amdgcn_cvt_f32_fp8(w, 2);
  out[3] = __builtin_amdgcn_cvt_f32_fp8(w, 3);
#else
  out[0] = fp8_manual((unsigned)w & 0xFFu);
  out[1] = fp8_manual(((unsigned)w >> 8) & 0xFFu);
  out[2] = fp8_manual(((unsigned)w >> 16) & 0xFFu);
  out[3] = fp8_manual(((unsigned)w >> 24) & 0xFFu);
#endif
}

// ---- DPP cross-lane (VALU pipe, not LDS) ----
template <int CTRL>
static __device__ __forceinline__ float dpp_mov(float x) {
  return __int_as_float(__builtin_amdgcn_update_dpp(
      0, __float_as_int(x), CTRL, 0xF, 0xF, true));
}
// 32-lane sum; valid in lanes 31 (half0) and 63 (half1).
static __device__ __forceinline__ float dpp_sum32_tail(float x) {
  x += dpp_mov<0x111>(x);   // row_shr:1
  x += dpp_mov<0x112>(x);   // row_shr:2
  x += dpp_mov<0x114>(x);   // row_shr:4
  x += dpp_mov<0x118>(x);   // row_shr:8
  x += dpp_mov<0x142>(x);   // row_bcast:15 (adds row0 total into row1)
  return x;
}
// 32-lane all-reduce (valid in all lanes of each 32-group): 4 DPP + 1 swizzle
static __device__ __forceinline__ float allred32_sum(float x) {
  x += dpp_mov<0xB1>(x);    // quad_perm xor1
  x += dpp_mov<0x4E>(x);    // quad_perm xor2
  x += dpp_mov<0x124>(x);   // row_ror:4
  x += dpp_mov<0x128>(x);   // row_ror:8
  x += __int_as_float(__builtin_amdgcn_ds_swizzle(__float_as_int(x), 0x401F)); // xor16
  return x;
}
static __device__ __forceinline__ float allred32_max(float x) {
  x = fmaxf(x, dpp_mov<0xB1>(x));
  x = fmaxf(x, dpp_mov<0x4E>(x));
  x = fmaxf(x, dpp_mov<0x124>(x));
  x = fmaxf(x, dpp_mov<0x128>(x));
  x = fmaxf(x, __int_as_float(__builtin_amdgcn_ds_swizzle(__float_as_int(x), 0x401F)));
  return x;
}

// dual-dtype loaders: f32flag=1 -> buffer holds float32, else bf16.
static __device__ __forceinline__ void load4any(const void* base, size_t idx, int f32flag, float* d) {
  if (f32flag) {
    float4 v = *(const float4*)((const float*)base + idx);
    d[0] = v.x; d[1] = v.y; d[2] = v.z; d[3] = v.w;
  } else {
    load4bf((const unsigned short*)base + idx, d);
  }
}
static __device__ __forceinline__ float load1any(const void* base, size_t idx, int f32flag) {
  return f32flag ? ((const float*)base)[idx] : b2f(((const unsigned short*)base)[idx]);
}

// flags[0]=1 iff float tensors are f32 (else bf16). flags[1]=1 iff x is int64 (else int32).
// One wave, parallel loads + shuffle reduce (was: 1 thread x 144 serial loads ~50us).
__global__ void detect(const unsigned short* __restrict__ W, const int* __restrict__ x,
                       int* __restrict__ flags) {
  const int l = threadIdx.x;
  int bad = 0;
#pragma unroll
  for (int i = l; i < 128; i += 64) {
    unsigned short u = W[i];
    if (u != 0) {
      int e = (u >> 7) & 0xFF;
      if (e < 90 || e > 128) bad++;
    }
  }
  int nz = (l < 16) ? (x[2 * l + 1] != 0 ? 1 : 0) : 0;
#pragma unroll
  for (int d = 1; d < 64; d <<= 1) {
    bad += __shfl_xor(bad, d);
    nz  += __shfl_xor(nz, d);
  }
  if (l == 0) {
    flags[0] = (bad > 8) ? 1 : 0;
    flags[1] = (nz == 0) ? 1 : 0;
  }
}

// feat[r,:] = [emb0[x0[r]] | emb1[x1[r]]] @ W + b   (65536 x 128, K=128)
// Writes fp8 table (full, coatt gather) + bf16 table (first NDST rows, h_self).
__global__ __launch_bounds__(256) void featgemm(
    const int* __restrict__ x,
    const void* __restrict__ emb0,
    const void* __restrict__ emb1,
    const void* __restrict__ W,
    const void* __restrict__ bvec,
    const int* __restrict__ flags,
    unsigned char* __restrict__ feat8,
    unsigned short* __restrict__ feat16)
{
  const int wf  = flags[0];
  const int x64 = flags[1];
  const int t = threadIdx.x;
  const int rt = t >> 5, ct = t & 31;
  const int r0 = blockIdx.x * 32 + rt * 4;
  const int c0 = ct * 4;

  float acc[4][4];
  float bv[4]; load4any(bvec, c0, wf, bv);
#pragma unroll
  for (int i = 0; i < 4; ++i)
#pragma unroll
    for (int j = 0; j < 4; ++j) acc[i][j] = bv[j];

  int x0[4], x1[4];
#pragma unroll
  for (int i = 0; i < 4; ++i) {
    if (x64) { x0[i] = x[(r0 + i) * 4]; x1[i] = x[(r0 + i) * 4 + 2]; }
    else     { x0[i] = x[(r0 + i) * 2]; x1[i] = x[(r0 + i) * 2 + 1]; }
  }

  float a[4][4], w[4];
  for (int k = 0; k < 32; k += 4) {
#pragma unroll
    for (int i = 0; i < 4; ++i) load4any(emb0, (size_t)x0[i] * 32 + k, wf, a[i]);
#pragma unroll
    for (int kk = 0; kk < 4; ++kk) {
      load4any(W, (size_t)(k + kk) * H + c0, wf, w);
#pragma unroll
      for (int i = 0; i < 4; ++i) {
        const float av = a[i][kk];
#pragma unroll
        for (int j = 0; j < 4; ++j) acc[i][j] += av * w[j];
      }
    }
  }
  for (int k = 32; k < 128; k += 4) {
#pragma unroll
    for (int i = 0; i < 4; ++i) load4any(emb1, (size_t)x1[i] * 96 + (k - 32), wf, a[i]);
#pragma unroll
    for (int kk = 0; kk < 4; ++kk) {
      load4any(W, (size_t)(k + kk) * H + c0, wf, w);
#pragma unroll
      for (int i = 0; i < 4; ++i) {
        const float av = a[i][kk];
#pragma unroll
        for (int j = 0; j < 4; ++j) acc[i][j] += av * w[j];
      }
    }
  }
#pragma unroll
  for (int i = 0; i < 4; ++i) {
    const int row = r0 + i;
    int p = __builtin_amdgcn_cvt_pk_fp8_f32(acc[i][0], acc[i][1], 0, false);
    p = __builtin_amdgcn_cvt_pk_fp8_f32(acc[i][2], acc[i][3], p, true);
    *(int*)(feat8 + (size_t)row * H + c0) = p;
    if (row < NDST) store4bf(feat16 + (size_t)row * H + c0, acc[i]);
  }
}

// Collapsed co-attention pool, one WAVE per node. fp8 gather + fp8 MFMA + DPP reductions.
__global__ __launch_bounds__(256) void coatt_mfma(
    const unsigned char* __restrict__ feat8,
    const unsigned short* __restrict__ feat16,
    const int* __restrict__ idxD,
    const int* __restrict__ idxQ,
    unsigned short* __restrict__ rst)
{
  __shared__ float gbuf[4][416];   // per wave: g[384] | sv[32]
  const int t = threadIdx.x;
  const int w = t >> 6;            // wave in block
  const int l = t & 63;            // lane
  const int r = l & 31;            // row index within D/Q tiles
  const int half = l >> 5;
  const int n = blockIdx.x * 4 + w;

  float* g   = gbuf[w];
  float* svb = gbuf[w] + 384;

  const int gD = idxD[n * 32 + r];
  const int gQ = idxQ[n * 32 + r];
  const unsigned char* drow = feat8 + (size_t)gD * H + half * 8;
  const unsigned char* qrow = feat8 + (size_t)gQ * H + half * 8;

  // A/B fragments for v_mfma_f32_32x32x16_fp8_fp8: lane holds X[row=l&31][k=(l>>5)*8+j].
  long dfrag[8], qfrag[8];
#pragma unroll
  for (int s = 0; s < 8; ++s) {
    dfrag[s] = *(const long*)(drow + s * 16);
    qfrag[s] = *(const long*)(qrow + s * 16);
  }

  f32x16 acc = {0,0,0,0,0,0,0,0,0,0,0,0,0,0,0,0};
#pragma unroll
  for (int s = 0; s < 8; ++s)
    acc = __builtin_amdgcn_mfma_f32_32x32x16_fp8_fp8(dfrag[s], qfrag[s], acc, 0, 0, 0);
  // L[m][k]: col k = l&31, row m = (reg&3) + 8*(reg>>2) + 4*half

  // ---- row softmax stats (AC, over k = the 32 lanes of this half): DPP all-reduce ----
  float er[16], rrcp[16];
#pragma unroll
  for (int i = 0; i < 16; ++i) {
    const float m = allred32_max(acc[i]);
    er[i] = __expf(acc[i] - m);
    rrcp[i] = 1.0f / allred32_sum(er[i]);
  }

  // ---- col softmax stats (AS, over m = 16 regs in-lane + partner lane l^32) ----
  float cmax = acc[0];
#pragma unroll
  for (int i = 1; i < 16; ++i) cmax = fmaxf(cmax, acc[i]);
  cmax = fmaxf(cmax, __shfl_xor(cmax, 32));
  float es[16], csum = 0.f;
#pragma unroll
  for (int i = 0; i < 16; ++i) { es[i] = __expf(acc[i] - cmax); csum += es[i]; }
  csum += __shfl_xor(csum, 32);
  const float crcp = 1.0f / csum;

  // sv[m] = sum_k AS[k,m]: DPP tail sums (valid lanes 31/63), staged to LDS
  float svt[16];
#pragma unroll
  for (int i = 0; i < 16; ++i) svt[i] = dpp_sum32_tail(es[i] * crcp);
  if (r == 31) {
    *(float4*)(svb + 4 * half)      = make_float4(svt[0],  svt[1],  svt[2],  svt[3]);
    *(float4*)(svb + 8 + 4 * half)  = make_float4(svt[4],  svt[5],  svt[6],  svt[7]);
    *(float4*)(svb + 16 + 4 * half) = make_float4(svt[8],  svt[9],  svt[10], svt[11]);
    *(float4*)(svb + 24 + 4 * half) = make_float4(svt[12], svt[13], svt[14], svt[15]);
  }
  // read back sv for this half's m-set (lgkmcnt dep within same wave) + own-row weight
  float sv16[16];
#pragma unroll
  for (int q = 0; q < 4; ++q) {
    float4 v = *(const float4*)(svb + q * 8 + 4 * half);
    sv16[q * 4] = v.x; sv16[q * 4 + 1] = v.y; sv16[q * 4 + 2] = v.z; sv16[q * 4 + 3] = v.w;
  }
  const float svl = svb[r];
  // tv[k] = sum_m sv[m]*AC[m,k]: in-lane over this half's 16 m + partner half
  float tvp = 0.f;
#pragma unroll
  for (int i = 0; i < 16; ++i) tvp += sv16[i] * er[i] * rrcp[i];
  const float tv = tvp + __shfl_xor(tvp, 32);

  // ---- pooled: g = [u | v | w]; u=sum_r Q, v=sum_r sv*D, w=sum_r tv*Q (DPP tails) ----
#pragma unroll
  for (int s = 0; s < 8; ++s) {
    int2 dw = *(int2*)&dfrag[s];
    int2 qw = *(int2*)&qfrag[s];
    float dv[8], qv[8];
    fp8x4_to_f32(dw.x, dv); fp8x4_to_f32(dw.y, dv + 4);
    fp8x4_to_f32(qw.x, qv); fp8x4_to_f32(qw.y, qv + 4);
    float uq[8], vd[8], wq[8];
#pragma unroll
    for (int j = 0; j < 8; ++j) {
      uq[j] = dpp_sum32_tail(qv[j]);
      vd[j] = dpp_sum32_tail(svl * dv[j]);
      wq[j] = dpp_sum32_tail(tv * qv[j]);
    }
    if (r == 31) {
      const int hb = s * 16 + half * 8;
      *(float4*)(g + hb)           = make_float4(uq[0], uq[1], uq[2], uq[3]);
      *(float4*)(g + hb + 4)       = make_float4(uq[4], uq[5], uq[6], uq[7]);
      *(float4*)(g + 128 + hb)     = make_float4(vd[0], vd[1], vd[2], vd[3]);
      *(float4*)(g + 128 + hb + 4) = make_float4(vd[4], vd[5], vd[6], vd[7]);
      *(float4*)(g + 256 + hb)     = make_float4(wq[0], wq[1], wq[2], wq[3]);
      *(float4*)(g + 256 + hb + 4) = make_float4(wq[4], wq[5], wq[6], wq[7]);
    }
  }

  // pooled[h'] = (g[3h'] + g[3h'+1] + g[3h'+2]) / 96 ;  rst = h_self + pooled
#pragma unroll
  for (int rep = 0; rep < 2; ++rep) {
    const int hp = l + rep * 64;
    const float p = (g[3 * hp] + g[3 * hp + 1] + g[3 * hp + 2]) * (1.0f / 96.0f);
    const float hs = b2f(feat16[(size_t)n * H + hp]);
    rst[(size_t)n * H + hp] = f2b(hs + p);
  }
}

// P1 = Wo_s@Wsc, P2 = Wo_c@Wcs, p1 = b_s@Wsc, p2 = b_c@Wcs
__global__ __launch_bounds__(128) void smallmm1(
    const void* __restrict__ Wos, const void* __restrict__ Woc,
    const void* __restrict__ Wsc, const void* __restrict__ Wcs,
    const void* __restrict__ bs, const void* __restrict__ bc,
    const int* __restrict__ flags,
    float* __restrict__ P1, float* __restrict__ P2,
    float* __restrict__ p1, float* __restrict__ p2)
{
  const int wf = flags[0];
  const int bid = blockIdx.x, c = threadIdx.x;
  if (bid < 128) {
    const int r = bid; float acc = 0.f;
    for (int k = 0; k < 128; ++k) acc += load1any(Wos, r * 128 + k, wf) * load1any(Wsc, k * 128 + c, wf);
    P1[r * 128 + c] = acc;
  } else if (bid < 256) {
    const int r = bid - 128; float acc = 0.f;
    for (int k = 0; k < 128; ++k) acc += load1any(Woc, r * 128 + k, wf) * load1any(Wcs, k * 128 + c, wf);
    P2[r * 128 + c] = acc;
  } else if (bid == 256) {
    float acc = 0.f;
    for (int k = 0; k < 128; ++k) acc += load1any(bs, k, wf) * load1any(Wsc, k * 128 + c, wf);
    p1[c] = acc;
  } else {
    float acc = 0.f;
    for (int k = 0; k < 128; ++k) acc += load1any(bc, k, wf) * load1any(Wcs, k * 128 + c, wf);
    p2[c] = acc;
  }
}

// Mss = C_SELF*Wo_s + C_DBL*P1@Wcs ; Mcc = C_SELF*Wo_c + C_DBL*P2@Wsc ; fused biases
__global__ __launch_bounds__(128) void smallmm2(
    const void* __restrict__ Wos, const void* __restrict__ Woc,
    const void* __restrict__ Wsc, const void* __restrict__ Wcs,
    const void* __restrict__ bs, const void* __restrict__ bc,
    const int* __restrict__ flags,
    const float* __restrict__ P1, const float* __restrict__ P2,
    const float* __restrict__ p1, const float* __restrict__ p2,
    float* __restrict__ Mss, float* __restrict__ Mcc,
    float* __restrict__ bsim, float* __restrict__ bcor)
{
  const int wf = flags[0];
  const int bid = blockIdx.x, c = threadIdx.x;
  if (bid < 128) {
    const int r = bid; float acc = 0.f;
    for (int k = 0; k < 128; ++k) acc += P1[r * 128 + k] * load1any(Wcs, k * 128 + c, wf);
    Mss[r * 128 + c] = C_SELF * load1any(Wos, r * 128 + c, wf) + C_DBL * acc;
  } else if (bid < 256) {
    const int r = bid - 128; float acc = 0.f;
    for (int k = 0; k < 128; ++k) acc += P2[r * 128 + k] * load1any(Wsc, k * 128 + c, wf);
    Mcc[r * 128 + c] = C_SELF * load1any(Woc, r * 128 + c, wf) + C_DBL * acc;
  } else if (bid == 256) {
    float acc = 0.f;
    for (int k = 0; k < 128; ++k) acc += p1[k] * load1any(Wcs, k * 128 + c, wf);
    bsim[c] = C_SELF * load1any(bs, c, wf) + C_CROSS * p2[c] + C_DBL * acc;
  } else {
    float acc = 0.f;
    for (int k = 0; k < 128; ++k) acc += p2[k] * load1any(Wsc, k * 128 + c, wf);
    bcor[c] = C_SELF * load1any(bc, c, wf) + C_CROSS * p1[c] + C_DBL * acc;
  }
}

// z2sim = Rs@Mss + C_CROSS*(Rc@P2) + bsim ; z2cor = Rc@Mcc + C_CROSS*(Rs@P1) + bcor
// OUTPUT IS FLOAT32.
__global__ __launch_bounds__(256) void finalmm(
    const unsigned short* __restrict__ Rs, const unsigned short* __restrict__ Rc,
    const float* __restrict__ Mss, const float* __restrict__ Mcc,
    const float* __restrict__ P1, const float* __restrict__ P2,
    const float* __restrict__ bsim, const float* __restrict__ bcor,
    float* __restrict__ outp)
{
  const int t = threadIdx.x;
  const int rt = t >> 5, ct = t & 31;
  const int r0 = blockIdx.x * 32 + rt * 4;
  const int c0 = ct * 4;
  float sA[4][4] = {}, sB[4][4] = {}, cA[4][4] = {}, cB[4][4] = {};

  for (int k = 0; k < 128; k += 4) {
    float a_s[4][4], a_c[4][4];
#pragma unroll
    for (int i = 0; i < 4; ++i) {
      load4bf(Rs + (size_t)(r0 + i) * H + k, a_s[i]);
      load4bf(Rc + (size_t)(r0 + i) * H + k, a_c[i]);
    }
#pragma unroll
    for (int kk = 0; kk < 4; ++kk) {
      float4 mss = *(const float4*)(Mss + (size_t)(k + kk) * H + c0);
      float4 mcc = *(const float4*)(Mcc + (size_t)(k + kk) * H + c0);
      float4 pp1 = *(const float4*)(P1 + (size_t)(k + kk) * H + c0);
      float4 pp2 = *(const float4*)(P2 + (size_t)(k + kk) * H + c0);
#pragma unroll
      for (int i = 0; i < 4; ++i) {
        const float as = a_s[i][kk], ac = a_c[i][kk];
        sA[i][0] += as * mss.x; sA[i][1] += as * mss.y; sA[i][2] += as * mss.z; sA[i][3] += as * mss.w;
        cB[i][0] += as * pp1.x; cB[i][1] += as * pp1.y; cB[i][2] += as * pp1.z; cB[i][3] += as * pp1.w;
        sB[i][0] += ac * pp2.x; sB[i][1] += ac * pp2.y; sB[i][2] += ac * pp2.z; sB[i][3] += ac * pp2.w;
        cA[i][0] += ac * mcc.x; cA[i][1] += ac * mcc.y; cA[i][2] += ac * mcc.z; cA[i][3] += ac * mcc.w;
      }
    }
  }
  float4 bsv = *(const float4*)(bsim + c0);
  float4 bcv = *(const float4*)(bcor + c0);
#pragma unroll
  for (int i = 0; i < 4; ++i) {
    float4 o1, o2;
    o1.x = sA[i][0] + C_CROSS * sB[i][0] + bsv.x;
    o1.y = sA[i][1] + C_CROSS * sB[i][1] + bsv.y;
    o1.z = sA[i][2] + C_CROSS * sB[i][2] + bsv.z;
    o1.w = sA[i][3] + C_CROSS * sB[i][3] + bsv.w;
    *(float4*)(outp + (size_t)(r0 + i) * H + c0) = o1;
    o2.x = cA[i][0] + C_CROSS * cB[i][0] + bcv.x;
    o2.y = cA[i][1] + C_CROSS * cB[i][1] + bcv.y;
    o2.z = cA[i][2] + C_CROSS * cB[i][2] + bcv.z;
    o2.w = cA[i][3] + C_CROSS * cB[i][3] + bcv.w;
    *(float4*)(outp + (size_t)NDST * H + (size_t)(r0 + i) * H + c0) = o2;
  }
}

extern "C" void kernel_launch(void* const* d_in, const int* in_sizes, int n_in,
                              void* d_out, int out_size, void* d_ws, size_t ws_size,
                              hipStream_t stream) {
  const int* x    = (const int*)d_in[0];
  const int* nsim = (const int*)d_in[1];
  const int* ncor = (const int*)d_in[2];
  const void* emb0_sim = d_in[3];
  const void* emb1_sim = d_in[4];
  const void* emb0_cor = d_in[5];
  const void* emb1_cor = d_in[6];
  const void* W_in_sim  = d_in[7];
  const void* b_in_sim  = d_in[8];
  const void* W_in_cor  = d_in[9];
  const void* b_in_cor  = d_in[10];
  const void* W_out_sim = d_in[11];
  const void* b_out_sim = d_in[12];
  const void* W_out_cor = d_in[13];
  const void* b_out_cor = d_in[14];
  const void* W_sim2cor = d_in[15];
  const void* W_cor2sim = d_in[16];

  // layout: f32 smalls | flags | bf16 tables | rst | fp8 tables
  float* fbase = (float*)d_ws;
  float* P1  = fbase;                   // 128*128 each
  float* P2  = P1 + H * H;
  float* Mss = P2 + H * H;
  float* Mcc = Mss + H * H;
  float* p1v = Mcc + H * H;             // 128 each
  float* p2v = p1v + H;
  float* bsimv = p2v + H;
  float* bcorv = bsimv + H;
  int* flags = (int*)(bcorv + H);       // 4 ints
  unsigned short* feat16_sim = (unsigned short*)(flags + 4);     // NDST*H
  unsigned short* feat16_cor = feat16_sim + (size_t)NDST * H;
  unsigned short* rst_sim    = feat16_cor + (size_t)NDST * H;    // NDST*H
  unsigned short* rst_cor    = rst_sim + (size_t)NDST * H;
  unsigned char* feat8_sim = (unsigned char*)(rst_cor + (size_t)NDST * H);  // NSRC*H bytes
  unsigned char* feat8_cor = feat8_sim + (size_t)NSRC * H;

  detect<<<1, 64, 0, stream>>>((const unsigned short*)W_in_sim, x, flags);
  smallmm1<<<258, 128, 0, stream>>>(W_out_sim, W_out_cor, W_sim2cor, W_cor2sim,
                                    b_out_sim, b_out_cor, flags, P1, P2, p1v, p2v);
  smallmm2<<<258, 128, 0, stream>>>(W_out_sim, W_out_cor, W_sim2cor, W_cor2sim,
                                    b_out_sim, b_out_cor, flags, P1, P2, p1v, p2v,
                                    Mss, Mcc, bsimv, bcorv);
  featgemm<<<NSRC / 32, 256, 0, stream>>>(x, emb0_sim, emb1_sim, W_in_sim, b_in_sim, flags,
                                          feat8_sim, feat16_sim);
  featgemm<<<NSRC / 32, 256, 0, stream>>>(x, emb0_cor, emb1_cor, W_in_cor, b_in_cor, flags,
                                          feat8_cor, feat16_cor);
  // mode 'sim': D = feat[neigh_cor], Q = feat[neigh_sim]
  coatt_mfma<<<NDST / 4, 256, 0, stream>>>(feat8_sim, feat16_sim, ncor, nsim, rst_sim);
  // mode 'cor': D = feat[neigh_sim], Q = feat[neigh_cor]
  coatt_mfma<<<NDST / 4, 256, 0, stream>>>(feat8_cor, feat16_cor, nsim, ncor, rst_cor);
  finalmm<<<NDST / 32, 256, 0, stream>>>(rst_sim, rst_cor, Mss, Mcc, P1, P2,
                                         bsimv, bcorv, (float*)d_out);
}

// Round 8
// 322.465 us; speedup vs baseline: 1.6684x; 1.2099x over previous
//
#include <hip/hip_runtime.h>
#include <hip/hip_bf16.h>

#define NSRC 65536
#define NDST 8192
#define H 128

// mixing constants: z2sim = 0.34*sim + 0.495*cor@Wcs + 0.165*sim@(Wsc@Wcs) (and sym.)
#define C_SELF 0.34f
#define C_CROSS 0.495f
#define C_DBL  0.165f

typedef float f32x16 __attribute__((ext_vector_type(16)));
typedef short bf16x8 __attribute__((ext_vector_type(8)));

static __device__ __forceinline__ float b2f(unsigned short u) {
  union { unsigned int i; float f; } v; v.i = ((unsigned int)u) << 16; return v.f;
}
static __device__ __forceinline__ unsigned short f2b(float f) {
  union { float f; unsigned int i; } v; v.f = f;
  unsigned int x = v.i;
  return (unsigned short)((x + 0x7fffu + ((x >> 16) & 1u)) >> 16);  // RNE
}
static __device__ __forceinline__ void load4bf(const unsigned short* p, float* d) {
  ushort4 u = *(const ushort4*)p;
  d[0] = b2f(u.x); d[1] = b2f(u.y); d[2] = b2f(u.z); d[3] = b2f(u.w);
}
static __device__ __forceinline__ void store4bf(unsigned short* p, const float* d) {
  ushort4 u; u.x = f2b(d[0]); u.y = f2b(d[1]); u.z = f2b(d[2]); u.w = f2b(d[3]);
  *(ushort4*)p = u;
}
// fp8 e4m3 x4 -> f32 (HW cvt if available; else manual incl. subnormals)
static __device__ __forceinline__ float fp8_manual(unsigned int b) {
  const unsigned e = (b >> 3) & 15u, m = b & 7u;
  union { unsigned i; float f; } v; v.i = ((e + 120u) << 23) | (m << 20);
  float f = (e == 0u) ? (float)m * 1.953125e-3f : v.f;
  return (b & 0x80u) ? -f : f;
}
static __device__ __forceinline__ void fp8x4_to_f32(int w, float* out) {
#if __has_builtin(__builtin_amdgcn_cvt_f32_fp8)
  out[0] = __builtin_amdgcn_cvt_f32_fp8(w, 0);
  out[1] = __builtin_amdgcn_cvt_f32_fp8(w, 1);
  out[2] = __builtin_amdgcn_cvt_f32_fp8(w, 2);
  out[3] = __builtin_amdgcn_cvt_f32_fp8(w, 3);
#else
  out[0] = fp8_manual((unsigned)w & 0xFFu);
  out[1] = fp8_manual(((unsigned)w >> 8) & 0xFFu);
  out[2] = fp8_manual(((unsigned)w >> 16) & 0xFFu);
  out[3] = fp8_manual(((unsigned)w >> 24) & 0xFFu);
#endif
}

// ---- DPP cross-lane (VALU pipe, not LDS) ----
template <int CTRL>
static __device__ __forceinline__ float dpp_mov(float x) {
  return __int_as_float(__builtin_amdgcn_update_dpp(
      0, __float_as_int(x), CTRL, 0xF, 0xF, true));
}
// 32-lane sum; valid in lanes 31 (half0) and 63 (half1).
static __device__ __forceinline__ float dpp_sum32_tail(float x) {
  x += dpp_mov<0x111>(x);   // row_shr:1
  x += dpp_mov<0x112>(x);   // row_shr:2
  x += dpp_mov<0x114>(x);   // row_shr:4
  x += dpp_mov<0x118>(x);   // row_shr:8
  x += dpp_mov<0x142>(x);   // row_bcast:15
  return x;
}
// 32-lane all-reduce: 4 DPP + 1 swizzle
static __device__ __forceinline__ float allred32_sum(float x) {
  x += dpp_mov<0xB1>(x);
  x += dpp_mov<0x4E>(x);
  x += dpp_mov<0x124>(x);
  x += dpp_mov<0x128>(x);
  x += __int_as_float(__builtin_amdgcn_ds_swizzle(__float_as_int(x), 0x401F));
  return x;
}
static __device__ __forceinline__ float allred32_max(float x) {
  x = fmaxf(x, dpp_mov<0xB1>(x));
  x = fmaxf(x, dpp_mov<0x4E>(x));
  x = fmaxf(x, dpp_mov<0x124>(x));
  x = fmaxf(x, dpp_mov<0x128>(x));
  x = fmaxf(x, __int_as_float(__builtin_amdgcn_ds_swizzle(__float_as_int(x), 0x401F)));
  return x;
}

// dual-dtype loaders: f32flag=1 -> buffer holds float32, else bf16.
static __device__ __forceinline__ void load4any(const void* base, size_t idx, int f32flag, float* d) {
  if (f32flag) {
    float4 v = *(const float4*)((const float*)base + idx);
    d[0] = v.x; d[1] = v.y; d[2] = v.z; d[3] = v.w;
  } else {
    load4bf((const unsigned short*)base + idx, d);
  }
}
static __device__ __forceinline__ float load1any(const void* base, size_t idx, int f32flag) {
  return f32flag ? ((const float*)base)[idx] : b2f(((const unsigned short*)base)[idx]);
}

// flags[0]=1 iff float tensors are f32 (else bf16). flags[1]=1 iff x is int64 (else int32).
__global__ void detect(const unsigned short* __restrict__ W, const int* __restrict__ x,
                       int* __restrict__ flags) {
  const int l = threadIdx.x;
  int bad = 0;
#pragma unroll
  for (int i = l; i < 128; i += 64) {
    unsigned short u = W[i];
    if (u != 0) {
      int e = (u >> 7) & 0xFF;
      if (e < 90 || e > 128) bad++;
    }
  }
  int nz = (l < 16) ? (x[2 * l + 1] != 0 ? 1 : 0) : 0;
#pragma unroll
  for (int d = 1; d < 64; d <<= 1) {
    bad += __shfl_xor(bad, d);
    nz  += __shfl_xor(nz, d);
  }
  if (l == 0) {
    flags[0] = (bad > 8) ? 1 : 0;
    flags[1] = (nz == 0) ? 1 : 0;
  }
}

// WT[n][k] = bf16(W[k][n]) for both modes; grid 256 x 128 threads.
__global__ __launch_bounds__(128) void wprep(
    const void* __restrict__ Wsim, const void* __restrict__ Wcor,
    const int* __restrict__ flags,
    unsigned short* __restrict__ WTsim, unsigned short* __restrict__ WTcor)
{
  const int wf = flags[0];
  const int n = blockIdx.x & 127;
  const void* W = (blockIdx.x & 128) ? Wcor : Wsim;
  unsigned short* WT = (blockIdx.x & 128) ? WTcor : WTsim;
  const int k = threadIdx.x;
  WT[n * 128 + k] = f2b(load1any(W, k * 128 + n, wf));
}

// feat = [emb0[x0]|emb1[x1]] @ W + b via bf16 MFMA.
// Block = 4 waves; wave w -> rows rowBlock*128 + w*32 .. +31, cols colStrip*32 .. +31.
// mfma(rowsOf(A), rowsOf(WT)) = A*WT^T = A*W  (operand idiom verified by coatt R5-7).
__global__ __launch_bounds__(256) void featgemm_mfma(
    const int* __restrict__ x,
    const void* __restrict__ emb0,
    const void* __restrict__ emb1,
    const unsigned short* __restrict__ WT,
    const void* __restrict__ bvec,
    const int* __restrict__ flags,
    unsigned char* __restrict__ feat8,
    unsigned short* __restrict__ feat16)
{
  const int wf  = flags[0];
  const int x64 = flags[1];
  const int t = threadIdx.x;
  const int w = t >> 6, l = t & 63, lane = l & 31, half = l >> 5;
  const int colStrip = blockIdx.x & 3;
  const int rowBlock = blockIdx.x >> 2;
  const int rbase = rowBlock * 128 + w * 32;
  const int r = rbase + lane;            // A row this lane gathers
  const int n = colStrip * 32 + lane;    // output col this lane owns

  int x0, x1;
  if (x64) { x0 = x[r * 4]; x1 = x[r * 4 + 2]; }
  else     { x0 = x[r * 2]; x1 = x[r * 2 + 1]; }

  // B fragments: WT row n, contiguous bf16.
  const unsigned short* wtrow = WT + (size_t)n * 128 + half * 8;
  bf16x8 bfrag[8];
#pragma unroll
  for (int s = 0; s < 8; ++s)
    bfrag[s] = *(const bf16x8*)(wtrow + s * 16);

  // A fragments: k = s*16 + half*8 + j. s=0,1 -> emb0[x0][k]; s>=2 -> emb1[x1][k-32].
  bf16x8 afrag[8];
#pragma unroll
  for (int s = 0; s < 8; ++s) {
    float tmp[8];
    if (s < 2) {
      const size_t base = (size_t)x0 * 32 + s * 16 + half * 8;
      load4any(emb0, base, wf, tmp);
      load4any(emb0, base + 4, wf, tmp + 4);
    } else {
      const size_t base = (size_t)x1 * 96 + (s * 16 - 32) + half * 8;
      load4any(emb1, base, wf, tmp);
      load4any(emb1, base + 4, wf, tmp + 4);
    }
    union { bf16x8 v; unsigned short u[8]; } cv;
#pragma unroll
    for (int j = 0; j < 8; ++j) cv.u[j] = f2b(tmp[j]);
    afrag[s] = cv.v;
  }

  f32x16 acc = {0,0,0,0,0,0,0,0,0,0,0,0,0,0,0,0};
#pragma unroll
  for (int s = 0; s < 8; ++s)
    acc = __builtin_amdgcn_mfma_f32_32x32x16_bf16(afrag[s], bfrag[s], acc, 0, 0, 0);
  // D[m][n]: n = lane, m = (reg&3) + 8*(reg>>2) + 4*half

  const float bias_n = load1any(bvec, n, wf);
  const bool do16 = (rbase < NDST);   // whole 32-row tile inside feat16 region or not
#pragma unroll
  for (int i = 0; i < 16; ++i) {
    const int m = (i & 3) + 8 * (i >> 2) + 4 * half;
    const int row = rbase + m;
    const float val = acc[i] + bias_n;
    const int p8 = __builtin_amdgcn_cvt_pk_fp8_f32(val, val, 0, false);
    feat8[(size_t)row * H + n] = (unsigned char)(p8 & 0xFF);
    if (do16) feat16[(size_t)row * H + n] = f2b(val);
  }
}

// Collapsed co-attention pool, one WAVE per node. fp8 gather + fp8 MFMA + DPP reductions.
__global__ __launch_bounds__(256) void coatt_mfma(
    const unsigned char* __restrict__ feat8,
    const unsigned short* __restrict__ feat16,
    const int* __restrict__ idxD,
    const int* __restrict__ idxQ,
    unsigned short* __restrict__ rst)
{
  __shared__ float gbuf[4][416];   // per wave: g[384] | sv[32]
  const int t = threadIdx.x;
  const int w = t >> 6;            // wave in block
  const int l = t & 63;            // lane
  const int r = l & 31;            // row index within D/Q tiles
  const int half = l >> 5;
  const int n = blockIdx.x * 4 + w;

  float* g   = gbuf[w];
  float* svb = gbuf[w] + 384;

  const int gD = idxD[n * 32 + r];
  const int gQ = idxQ[n * 32 + r];
  const unsigned char* drow = feat8 + (size_t)gD * H + half * 8;
  const unsigned char* qrow = feat8 + (size_t)gQ * H + half * 8;

  long dfrag[8], qfrag[8];
#pragma unroll
  for (int s = 0; s < 8; ++s) {
    dfrag[s] = *(const long*)(drow + s * 16);
    qfrag[s] = *(const long*)(qrow + s * 16);
  }

  f32x16 acc = {0,0,0,0,0,0,0,0,0,0,0,0,0,0,0,0};
#pragma unroll
  for (int s = 0; s < 8; ++s)
    acc = __builtin_amdgcn_mfma_f32_32x32x16_fp8_fp8(dfrag[s], qfrag[s], acc, 0, 0, 0);
  // L[m][k]: col k = l&31, row m = (reg&3) + 8*(reg>>2) + 4*half

  // ---- row softmax stats (AC, over k): DPP all-reduce ----
  float er[16], rrcp[16];
#pragma unroll
  for (int i = 0; i < 16; ++i) {
    const float m = allred32_max(acc[i]);
    er[i] = __expf(acc[i] - m);
    rrcp[i] = 1.0f / allred32_sum(er[i]);
  }

  // ---- col softmax stats (AS, over m = 16 regs in-lane + partner lane l^32) ----
  float cmax = acc[0];
#pragma unroll
  for (int i = 1; i < 16; ++i) cmax = fmaxf(cmax, acc[i]);
  cmax = fmaxf(cmax, __shfl_xor(cmax, 32));
  float es[16], csum = 0.f;
#pragma unroll
  for (int i = 0; i < 16; ++i) { es[i] = __expf(acc[i] - cmax); csum += es[i]; }
  csum += __shfl_xor(csum, 32);
  const float crcp = 1.0f / csum;

  // sv[m] = sum_k AS[k,m]: DPP tail sums, staged to LDS
  float svt[16];
#pragma unroll
  for (int i = 0; i < 16; ++i) svt[i] = dpp_sum32_tail(es[i] * crcp);
  if (r == 31) {
    *(float4*)(svb + 4 * half)      = make_float4(svt[0],  svt[1],  svt[2],  svt[3]);
    *(float4*)(svb + 8 + 4 * half)  = make_float4(svt[4],  svt[5],  svt[6],  svt[7]);
    *(float4*)(svb + 16 + 4 * half) = make_float4(svt[8],  svt[9],  svt[10], svt[11]);
    *(float4*)(svb + 24 + 4 * half) = make_float4(svt[12], svt[13], svt[14], svt[15]);
  }
  float sv16[16];
#pragma unroll
  for (int q = 0; q < 4; ++q) {
    float4 v = *(const float4*)(svb + q * 8 + 4 * half);
    sv16[q * 4] = v.x; sv16[q * 4 + 1] = v.y; sv16[q * 4 + 2] = v.z; sv16[q * 4 + 3] = v.w;
  }
  const float svl = svb[r];
  float tvp = 0.f;
#pragma unroll
  for (int i = 0; i < 16; ++i) tvp += sv16[i] * er[i] * rrcp[i];
  const float tv = tvp + __shfl_xor(tvp, 32);

  // ---- pooled: g = [u | v | w] (DPP tails) ----
#pragma unroll
  for (int s = 0; s < 8; ++s) {
    int2 dw = *(int2*)&dfrag[s];
    int2 qw = *(int2*)&qfrag[s];
    float dv[8], qv[8];
    fp8x4_to_f32(dw.x, dv); fp8x4_to_f32(dw.y, dv + 4);
    fp8x4_to_f32(qw.x, qv); fp8x4_to_f32(qw.y, qv + 4);
    float uq[8], vd[8], wq[8];
#pragma unroll
    for (int j = 0; j < 8; ++j) {
      uq[j] = dpp_sum32_tail(qv[j]);
      vd[j] = dpp_sum32_tail(svl * dv[j]);
      wq[j] = dpp_sum32_tail(tv * qv[j]);
    }
    if (r == 31) {
      const int hb = s * 16 + half * 8;
      *(float4*)(g + hb)           = make_float4(uq[0], uq[1], uq[2], uq[3]);
      *(float4*)(g + hb + 4)       = make_float4(uq[4], uq[5], uq[6], uq[7]);
      *(float4*)(g + 128 + hb)     = make_float4(vd[0], vd[1], vd[2], vd[3]);
      *(float4*)(g + 128 + hb + 4) = make_float4(vd[4], vd[5], vd[6], vd[7]);
      *(float4*)(g + 256 + hb)     = make_float4(wq[0], wq[1], wq[2], wq[3]);
      *(float4*)(g + 256 + hb + 4) = make_float4(wq[4], wq[5], wq[6], wq[7]);
    }
  }

#pragma unroll
  for (int rep = 0; rep < 2; ++rep) {
    const int hp = l + rep * 64;
    const float p = (g[3 * hp] + g[3 * hp + 1] + g[3 * hp + 2]) * (1.0f / 96.0f);
    const float hs = b2f(feat16[(size_t)n * H + hp]);
    rst[(size_t)n * H + hp] = f2b(hs + p);
  }
}

// P1 = Wo_s@Wsc, P2 = Wo_c@Wcs, p1 = b_s@Wsc, p2 = b_c@Wcs
__global__ __launch_bounds__(128) void smallmm1(
    const void* __restrict__ Wos, const void* __restrict__ Woc,
    const void* __restrict__ Wsc, const void* __restrict__ Wcs,
    const void* __restrict__ bs, const void* __restrict__ bc,
    const int* __restrict__ flags,
    float* __restrict__ P1, float* __restrict__ P2,
    float* __restrict__ p1, float* __restrict__ p2)
{
  const int wf = flags[0];
  const int bid = blockIdx.x, c = threadIdx.x;
  if (bid < 128) {
    const int r = bid; float acc = 0.f;
    for (int k = 0; k < 128; ++k) acc += load1any(Wos, r * 128 + k, wf) * load1any(Wsc, k * 128 + c, wf);
    P1[r * 128 + c] = acc;
  } else if (bid < 256) {
    const int r = bid - 128; float acc = 0.f;
    for (int k = 0; k < 128; ++k) acc += load1any(Woc, r * 128 + k, wf) * load1any(Wcs, k * 128 + c, wf);
    P2[r * 128 + c] = acc;
  } else if (bid == 256) {
    float acc = 0.f;
    for (int k = 0; k < 128; ++k) acc += load1any(bs, k, wf) * load1any(Wsc, k * 128 + c, wf);
    p1[c] = acc;
  } else {
    float acc = 0.f;
    for (int k = 0; k < 128; ++k) acc += load1any(bc, k, wf) * load1any(Wcs, k * 128 + c, wf);
    p2[c] = acc;
  }
}

// Mss = C_SELF*Wo_s + C_DBL*P1@Wcs ; Mcc = C_SELF*Wo_c + C_DBL*P2@Wsc ; fused biases
__global__ __launch_bounds__(128) void smallmm2(
    const void* __restrict__ Wos, const void* __restrict__ Woc,
    const void* __restrict__ Wsc, const void* __restrict__ Wcs,
    const void* __restrict__ bs, const void* __restrict__ bc,
    const int* __restrict__ flags,
    const float* __restrict__ P1, const float* __restrict__ P2,
    const float* __restrict__ p1, const float* __restrict__ p2,
    float* __restrict__ Mss, float* __restrict__ Mcc,
    float* __restrict__ bsim, float* __restrict__ bcor)
{
  const int wf = flags[0];
  const int bid = blockIdx.x, c = threadIdx.x;
  if (bid < 128) {
    const int r = bid; float acc = 0.f;
    for (int k = 0; k < 128; ++k) acc += P1[r * 128 + k] * load1any(Wcs, k * 128 + c, wf);
    Mss[r * 128 + c] = C_SELF * load1any(Wos, r * 128 + c, wf) + C_DBL * acc;
  } else if (bid < 256) {
    const int r = bid - 128; float acc = 0.f;
    for (int k = 0; k < 128; ++k) acc += P2[r * 128 + k] * load1any(Wsc, k * 128 + c, wf);
    Mcc[r * 128 + c] = C_SELF * load1any(Woc, r * 128 + c, wf) + C_DBL * acc;
  } else if (bid == 256) {
    float acc = 0.f;
    for (int k = 0; k < 128; ++k) acc += p1[k] * load1any(Wcs, k * 128 + c, wf);
    bsim[c] = C_SELF * load1any(bs, c, wf) + C_CROSS * p2[c] + C_DBL * acc;
  } else {
    float acc = 0.f;
    for (int k = 0; k < 128; ++k) acc += p2[k] * load1any(Wsc, k * 128 + c, wf);
    bcor[c] = C_SELF * load1any(bc, c, wf) + C_CROSS * p1[c] + C_DBL * acc;
  }
}

// z2sim = Rs@Mss + C_CROSS*(Rc@P2) + bsim ; z2cor = Rc@Mcc + C_CROSS*(Rs@P1) + bcor
// OUTPUT IS FLOAT32.
__global__ __launch_bounds__(256) void finalmm(
    const unsigned short* __restrict__ Rs, const unsigned short* __restrict__ Rc,
    const float* __restrict__ Mss, const float* __restrict__ Mcc,
    const float* __restrict__ P1, const float* __restrict__ P2,
    const float* __restrict__ bsim, const float* __restrict__ bcor,
    float* __restrict__ outp)
{
  const int t = threadIdx.x;
  const int rt = t >> 5, ct = t & 31;
  const int r0 = blockIdx.x * 32 + rt * 4;
  const int c0 = ct * 4;
  float sA[4][4] = {}, sB[4][4] = {}, cA[4][4] = {}, cB[4][4] = {};

  for (int k = 0; k < 128; k += 4) {
    float a_s[4][4], a_c[4][4];
#pragma unroll
    for (int i = 0; i < 4; ++i) {
      load4bf(Rs + (size_t)(r0 + i) * H + k, a_s[i]);
      load4bf(Rc + (size_t)(r0 + i) * H + k, a_c[i]);
    }
#pragma unroll
    for (int kk = 0; kk < 4; ++kk) {
      float4 mss = *(const float4*)(Mss + (size_t)(k + kk) * H + c0);
      float4 mcc = *(const float4*)(Mcc + (size_t)(k + kk) * H + c0);
      float4 pp1 = *(const float4*)(P1 + (size_t)(k + kk) * H + c0);
      float4 pp2 = *(const float4*)(P2 + (size_t)(k + kk) * H + c0);
#pragma unroll
      for (int i = 0; i < 4; ++i) {
        const float as = a_s[i][kk], ac = a_c[i][kk];
        sA[i][0] += as * mss.x; sA[i][1] += as * mss.y; sA[i][2] += as * mss.z; sA[i][3] += as * mss.w;
        cB[i][0] += as * pp1.x; cB[i][1] += as * pp1.y; cB[i][2] += as * pp1.z; cB[i][3] += as * pp1.w;
        sB[i][0] += ac * pp2.x; sB[i][1] += ac * pp2.y; sB[i][2] += ac * pp2.z; sB[i][3] += ac * pp2.w;
        cA[i][0] += ac * mcc.x; cA[i][1] += ac * mcc.y; cA[i][2] += ac * mcc.z; cA[i][3] += ac * mcc.w;
      }
    }
  }
  float4 bsv = *(const float4*)(bsim + c0);
  float4 bcv = *(const float4*)(bcor + c0);
#pragma unroll
  for (int i = 0; i < 4; ++i) {
    float4 o1, o2;
    o1.x = sA[i][0] + C_CROSS * sB[i][0] + bsv.x;
    o1.y = sA[i][1] + C_CROSS * sB[i][1] + bsv.y;
    o1.z = sA[i][2] + C_CROSS * sB[i][2] + bsv.z;
    o1.w = sA[i][3] + C_CROSS * sB[i][3] + bsv.w;
    *(float4*)(outp + (size_t)(r0 + i) * H + c0) = o1;
    o2.x = cA[i][0] + C_CROSS * cB[i][0] + bcv.x;
    o2.y = cA[i][1] + C_CROSS * cB[i][1] + bcv.y;
    o2.z = cA[i][2] + C_CROSS * cB[i][2] + bcv.z;
    o2.w = cA[i][3] + C_CROSS * cB[i][3] + bcv.w;
    *(float4*)(outp + (size_t)NDST * H + (size_t)(r0 + i) * H + c0) = o2;
  }
}

extern "C" void kernel_launch(void* const* d_in, const int* in_sizes, int n_in,
                              void* d_out, int out_size, void* d_ws, size_t ws_size,
                              hipStream_t stream) {
  const int* x    = (const int*)d_in[0];
  const int* nsim = (const int*)d_in[1];
  const int* ncor = (const int*)d_in[2];
  const void* emb0_sim = d_in[3];
  const void* emb1_sim = d_in[4];
  const void* emb0_cor = d_in[5];
  const void* emb1_cor = d_in[6];
  const void* W_in_sim  = d_in[7];
  const void* b_in_sim  = d_in[8];
  const void* W_in_cor  = d_in[9];
  const void* b_in_cor  = d_in[10];
  const void* W_out_sim = d_in[11];
  const void* b_out_sim = d_in[12];
  const void* W_out_cor = d_in[13];
  const void* b_out_cor = d_in[14];
  const void* W_sim2cor = d_in[15];
  const void* W_cor2sim = d_in[16];

  // layout: f32 smalls | flags | bf16 tables | rst | fp8 tables | WT bf16
  float* fbase = (float*)d_ws;
  float* P1  = fbase;                   // 128*128 each
  float* P2  = P1 + H * H;
  float* Mss = P2 + H * H;
  float* Mcc = Mss + H * H;
  float* p1v = Mcc + H * H;             // 128 each
  float* p2v = p1v + H;
  float* bsimv = p2v + H;
  float* bcorv = bsimv + H;
  int* flags = (int*)(bcorv + H);       // 4 ints
  unsigned short* feat16_sim = (unsigned short*)(flags + 4);     // NDST*H
  unsigned short* feat16_cor = feat16_sim + (size_t)NDST * H;
  unsigned short* rst_sim    = feat16_cor + (size_t)NDST * H;    // NDST*H
  unsigned short* rst_cor    = rst_sim + (size_t)NDST * H;
  unsigned char* feat8_sim = (unsigned char*)(rst_cor + (size_t)NDST * H);  // NSRC*H bytes
  unsigned char* feat8_cor = feat8_sim + (size_t)NSRC * H;
  unsigned short* WT_sim = (unsigned short*)(feat8_cor + (size_t)NSRC * H); // 128*128 bf16
  unsigned short* WT_cor = WT_sim + H * H;

  detect<<<1, 64, 0, stream>>>((const unsigned short*)W_in_sim, x, flags);
  wprep<<<256, 128, 0, stream>>>(W_in_sim, W_in_cor, flags, WT_sim, WT_cor);
  smallmm1<<<258, 128, 0, stream>>>(W_out_sim, W_out_cor, W_sim2cor, W_cor2sim,
                                    b_out_sim, b_out_cor, flags, P1, P2, p1v, p2v);
  smallmm2<<<258, 128, 0, stream>>>(W_out_sim, W_out_cor, W_sim2cor, W_cor2sim,
                                    b_out_sim, b_out_cor, flags, P1, P2, p1v, p2v,
                                    Mss, Mcc, bsimv, bcorv);
  featgemm_mfma<<<(NSRC / 128) * 4, 256, 0, stream>>>(x, emb0_sim, emb1_sim, WT_sim, b_in_sim,
                                                      flags, feat8_sim, feat16_sim);
  featgemm_mfma<<<(NSRC / 128) * 4, 256, 0, stream>>>(x, emb0_cor, emb1_cor, WT_cor, b_in_cor,
                                                      flags, feat8_cor, feat16_cor);
  // mode 'sim': D = feat[neigh_cor], Q = feat[neigh_sim]
  coatt_mfma<<<NDST / 4, 256, 0, stream>>>(feat8_sim, feat16_sim, ncor, nsim, rst_sim);
  // mode 'cor': D = feat[neigh_sim], Q = feat[neigh_cor]
  coatt_mfma<<<NDST / 4, 256, 0, stream>>>(feat8_cor, feat16_cor, nsim, ncor, rst_cor);
  finalmm<<<NDST / 32, 256, 0, stream>>>(rst_sim, rst_cor, Mss, Mcc, P1, P2,
                                         bsimv, bcorv, (float*)d_out);
}

// Round 9
// 268.803 us; speedup vs baseline: 2.0015x; 1.1996x over previous
//
#include <hip/hip_runtime.h>
#include <hip/hip_bf16.h>

#define NSRC 65536
#define NDST 8192
#define H 128

// mixing constants: z2sim = 0.34*sim + 0.495*cor@Wcs + 0.165*sim@(Wsc@Wcs) (and sym.)
#define C_SELF 0.34f
#define C_CROSS 0.495f
#define C_DBL  0.165f

typedef float f32x16 __attribute__((ext_vector_type(16)));
typedef short bf16x8 __attribute__((ext_vector_type(8)));

static __device__ __forceinline__ float b2f(unsigned short u) {
  union { unsigned int i; float f; } v; v.i = ((unsigned int)u) << 16; return v.f;
}
static __device__ __forceinline__ unsigned short f2b(float f) {
  union { float f; unsigned int i; } v; v.f = f;
  unsigned int x = v.i;
  return (unsigned short)((x + 0x7fffu + ((x >> 16) & 1u)) >> 16);  // RNE
}
static __device__ __forceinline__ void load4bf(const unsigned short* p, float* d) {
  ushort4 u = *(const ushort4*)p;
  d[0] = b2f(u.x); d[1] = b2f(u.y); d[2] = b2f(u.z); d[3] = b2f(u.w);
}
// fp8 e4m3 x4 -> f32 (HW cvt if available; else manual incl. subnormals)
static __device__ __forceinline__ float fp8_manual(unsigned int b) {
  const unsigned e = (b >> 3) & 15u, m = b & 7u;
  union { unsigned i; float f; } v; v.i = ((e + 120u) << 23) | (m << 20);
  float f = (e == 0u) ? (float)m * 1.953125e-3f : v.f;
  return (b & 0x80u) ? -f : f;
}
static __device__ __forceinline__ void fp8x4_to_f32(int w, float* out) {
#if __has_builtin(__builtin_amdgcn_cvt_f32_fp8)
  out[0] = __builtin_amdgcn_cvt_f32_fp8(w, 0);
  out[1] = __builtin_amdgcn_cvt_f32_fp8(w, 1);
  out[2] = __builtin_amdgcn_cvt_f32_fp8(w, 2);
  out[3] = __builtin_amdgcn_cvt_f32_fp8(w, 3);
#else
  out[0] = fp8_manual((unsigned)w & 0xFFu);
  out[1] = fp8_manual(((unsigned)w >> 8) & 0xFFu);
  out[2] = fp8_manual(((unsigned)w >> 16) & 0xFFu);
  out[3] = fp8_manual(((unsigned)w >> 24) & 0xFFu);
#endif
}

// ---- DPP cross-lane (VALU pipe, not LDS) ----
template <int CTRL>
static __device__ __forceinline__ float dpp_mov(float x) {
  return __int_as_float(__builtin_amdgcn_update_dpp(
      0, __float_as_int(x), CTRL, 0xF, 0xF, true));
}
// 32-lane sum; valid in lanes 31 (half0) and 63 (half1).
static __device__ __forceinline__ float dpp_sum32_tail(float x) {
  x += dpp_mov<0x111>(x);   // row_shr:1
  x += dpp_mov<0x112>(x);   // row_shr:2
  x += dpp_mov<0x114>(x);   // row_shr:4
  x += dpp_mov<0x118>(x);   // row_shr:8
  x += dpp_mov<0x142>(x);   // row_bcast:15
  return x;
}
// 32-lane all-reduce sum: 4 DPP + 1 swizzle
static __device__ __forceinline__ float allred32_sum(float x) {
  x += dpp_mov<0xB1>(x);
  x += dpp_mov<0x4E>(x);
  x += dpp_mov<0x124>(x);
  x += dpp_mov<0x128>(x);
  x += __int_as_float(__builtin_amdgcn_ds_swizzle(__float_as_int(x), 0x401F));
  return x;
}

// dual-dtype loaders: f32flag=1 -> buffer holds float32, else bf16.
static __device__ __forceinline__ void load4any(const void* base, size_t idx, int f32flag, float* d) {
  if (f32flag) {
    float4 v = *(const float4*)((const float*)base + idx);
    d[0] = v.x; d[1] = v.y; d[2] = v.z; d[3] = v.w;
  } else {
    load4bf((const unsigned short*)base + idx, d);
  }
}
static __device__ __forceinline__ float load1any(const void* base, size_t idx, int f32flag) {
  return f32flag ? ((const float*)base)[idx] : b2f(((const unsigned short*)base)[idx]);
}

// flags[0]=1 iff float tensors are f32 (else bf16). flags[1]=1 iff x is int64 (else int32).
__global__ void detect(const unsigned short* __restrict__ W, const int* __restrict__ x,
                       int* __restrict__ flags) {
  const int l = threadIdx.x;
  int bad = 0;
#pragma unroll
  for (int i = l; i < 128; i += 64) {
    unsigned short u = W[i];
    if (u != 0) {
      int e = (u >> 7) & 0xFF;
      if (e < 90 || e > 128) bad++;
    }
  }
  int nz = (l < 16) ? (x[2 * l + 1] != 0 ? 1 : 0) : 0;
#pragma unroll
  for (int d = 1; d < 64; d <<= 1) {
    bad += __shfl_xor(bad, d);
    nz  += __shfl_xor(nz, d);
  }
  if (l == 0) {
    flags[0] = (bad > 8) ? 1 : 0;
    flags[1] = (nz == 0) ? 1 : 0;
  }
}

// WT[n][k] = bf16(W[k][n]) for both modes; grid 256 x 128 threads.
__global__ __launch_bounds__(128) void wprep(
    const void* __restrict__ Wsim, const void* __restrict__ Wcor,
    const int* __restrict__ flags,
    unsigned short* __restrict__ WTsim, unsigned short* __restrict__ WTcor)
{
  const int wf = flags[0];
  const int n = blockIdx.x & 127;
  const void* W = (blockIdx.x & 128) ? Wcor : Wsim;
  unsigned short* WT = (blockIdx.x & 128) ? WTcor : WTsim;
  const int k = threadIdx.x;
  WT[n * 128 + k] = f2b(load1any(W, k * 128 + n, wf));
}

// feat = [emb0[x0]|emb1[x1]] @ W + b via bf16 MFMA.
// Block = 4 waves x 32 rows each (128 rows/block); each WAVE covers all 128 cols
// in 4 strips, reusing its A fragments (gather+cvt amortized 4x).
__global__ __launch_bounds__(256) void featgemm_mfma(
    const int* __restrict__ x,
    const void* __restrict__ emb0,
    const void* __restrict__ emb1,
    const unsigned short* __restrict__ WT,
    const void* __restrict__ bvec,
    const int* __restrict__ flags,
    unsigned char* __restrict__ feat8,
    unsigned short* __restrict__ feat16)
{
  const int wf  = flags[0];
  const int x64 = flags[1];
  const int t = threadIdx.x;
  const int w = t >> 6, l = t & 63, lane = l & 31, half = l >> 5;
  const int rbase = blockIdx.x * 128 + w * 32;
  const int r = rbase + lane;            // A row this lane gathers

  int x0, x1;
  if (x64) { x0 = x[r * 4]; x1 = x[r * 4 + 2]; }
  else     { x0 = x[r * 2]; x1 = x[r * 2 + 1]; }

  // A fragments: k = s*16 + half*8 + j. s=0,1 -> emb0[x0][k]; s>=2 -> emb1[x1][k-32].
  bf16x8 afrag[8];
#pragma unroll
  for (int s = 0; s < 8; ++s) {
    float tmp[8];
    if (s < 2) {
      const size_t base = (size_t)x0 * 32 + s * 16 + half * 8;
      load4any(emb0, base, wf, tmp);
      load4any(emb0, base + 4, wf, tmp + 4);
    } else {
      const size_t base = (size_t)x1 * 96 + (s * 16 - 32) + half * 8;
      load4any(emb1, base, wf, tmp);
      load4any(emb1, base + 4, wf, tmp + 4);
    }
    union { bf16x8 v; unsigned short u[8]; } cv;
#pragma unroll
    for (int j = 0; j < 8; ++j) cv.u[j] = f2b(tmp[j]);
    afrag[s] = cv.v;
  }

  const bool do16 = (rbase < NDST);
#pragma unroll
  for (int strip = 0; strip < 4; ++strip) {
    const int n = strip * 32 + lane;
    const unsigned short* wtrow = WT + (size_t)n * 128 + half * 8;
    f32x16 acc = {0,0,0,0,0,0,0,0,0,0,0,0,0,0,0,0};
#pragma unroll
    for (int s = 0; s < 8; ++s) {
      bf16x8 bfrag = *(const bf16x8*)(wtrow + s * 16);
      acc = __builtin_amdgcn_mfma_f32_32x32x16_bf16(afrag[s], bfrag, acc, 0, 0, 0);
    }
    const float bias_n = load1any(bvec, n, wf);
#pragma unroll
    for (int i = 0; i < 16; ++i) {
      const int m = (i & 3) + 8 * (i >> 2) + 4 * half;
      const int row = rbase + m;
      const float val = acc[i] + bias_n;
      const int p8 = __builtin_amdgcn_cvt_pk_fp8_f32(val, val, 0, false);
      feat8[(size_t)row * H + n] = (unsigned char)(p8 & 0xFF);
      if (do16) feat16[(size_t)row * H + n] = f2b(val);
    }
  }
}

// Collapsed co-attention pool, one WAVE per node. fp8 gather + fp8 MFMA + DPP reductions.
// No max-subtraction: |L| <= 128*0.07^2 ~ 0.6 so exp is safe; AC/AS share exp(L).
__global__ __launch_bounds__(256) void coatt_mfma(
    const unsigned char* __restrict__ feat8,
    const unsigned short* __restrict__ feat16,
    const int* __restrict__ idxD,
    const int* __restrict__ idxQ,
    unsigned short* __restrict__ rst)
{
  __shared__ float gbuf[4][416];   // per wave: g[384] | sv[32]
  const int t = threadIdx.x;
  const int w = t >> 6;            // wave in block
  const int l = t & 63;            // lane
  const int r = l & 31;            // row index within D/Q tiles
  const int half = l >> 5;
  const int n = blockIdx.x * 4 + w;

  float* g   = gbuf[w];
  float* svb = gbuf[w] + 384;

  const int gD = idxD[n * 32 + r];
  const int gQ = idxQ[n * 32 + r];
  const unsigned char* drow = feat8 + (size_t)gD * H + half * 8;
  const unsigned char* qrow = feat8 + (size_t)gQ * H + half * 8;

  long dfrag[8], qfrag[8];
#pragma unroll
  for (int s = 0; s < 8; ++s) {
    dfrag[s] = *(const long*)(drow + s * 16);
    qfrag[s] = *(const long*)(qrow + s * 16);
  }

  f32x16 acc = {0,0,0,0,0,0,0,0,0,0,0,0,0,0,0,0};
#pragma unroll
  for (int s = 0; s < 8; ++s)
    acc = __builtin_amdgcn_mfma_f32_32x32x16_fp8_fp8(dfrag[s], qfrag[s], acc, 0, 0, 0);
  // L[m][k]: col k = l&31, row m = (reg&3) + 8*(reg>>2) + 4*half

  // exp(L) once, shared by AC and AS
  float ex[16], rrcp[16];
#pragma unroll
  for (int i = 0; i < 16; ++i) ex[i] = __expf(acc[i]);
  // row softmax denominators (over k = 32 lanes of this half)
#pragma unroll
  for (int i = 0; i < 16; ++i) rrcp[i] = 1.0f / allred32_sum(ex[i]);
  // col denominators (over m = 16 regs in-lane + partner lane l^32)
  float csum = 0.f;
#pragma unroll
  for (int i = 0; i < 16; ++i) csum += ex[i];
  csum += __shfl_xor(csum, 32);
  const float crcp = 1.0f / csum;

  // sv[m] = sum_k AS[k,m]: DPP tail sums, staged to LDS
  float svt[16];
#pragma unroll
  for (int i = 0; i < 16; ++i) svt[i] = dpp_sum32_tail(ex[i] * crcp);
  if (r == 31) {
    *(float4*)(svb + 4 * half)      = make_float4(svt[0],  svt[1],  svt[2],  svt[3]);
    *(float4*)(svb + 8 + 4 * half)  = make_float4(svt[4],  svt[5],  svt[6],  svt[7]);
    *(float4*)(svb + 16 + 4 * half) = make_float4(svt[8],  svt[9],  svt[10], svt[11]);
    *(float4*)(svb + 24 + 4 * half) = make_float4(svt[12], svt[13], svt[14], svt[15]);
  }
  float sv16[16];
#pragma unroll
  for (int q = 0; q < 4; ++q) {
    float4 v = *(const float4*)(svb + q * 8 + 4 * half);
    sv16[q * 4] = v.x; sv16[q * 4 + 1] = v.y; sv16[q * 4 + 2] = v.z; sv16[q * 4 + 3] = v.w;
  }
  const float svl = svb[r];
  float tvp = 0.f;
#pragma unroll
  for (int i = 0; i < 16; ++i) tvp += sv16[i] * ex[i] * rrcp[i];
  const float tv = tvp + __shfl_xor(tvp, 32);

  // ---- pooled: g = [u | v | w] (DPP tails) ----
#pragma unroll
  for (int s = 0; s < 8; ++s) {
    int2 dw = *(int2*)&dfrag[s];
    int2 qw = *(int2*)&qfrag[s];
    float dv[8], qv[8];
    fp8x4_to_f32(dw.x, dv); fp8x4_to_f32(dw.y, dv + 4);
    fp8x4_to_f32(qw.x, qv); fp8x4_to_f32(qw.y, qv + 4);
    float uq[8], vd[8], wq[8];
#pragma unroll
    for (int j = 0; j < 8; ++j) {
      uq[j] = dpp_sum32_tail(qv[j]);
      vd[j] = dpp_sum32_tail(svl * dv[j]);
      wq[j] = dpp_sum32_tail(tv * qv[j]);
    }
    if (r == 31) {
      const int hb = s * 16 + half * 8;
      *(float4*)(g + hb)           = make_float4(uq[0], uq[1], uq[2], uq[3]);
      *(float4*)(g + hb + 4)       = make_float4(uq[4], uq[5], uq[6], uq[7]);
      *(float4*)(g + 128 + hb)     = make_float4(vd[0], vd[1], vd[2], vd[3]);
      *(float4*)(g + 128 + hb + 4) = make_float4(vd[4], vd[5], vd[6], vd[7]);
      *(float4*)(g + 256 + hb)     = make_float4(wq[0], wq[1], wq[2], wq[3]);
      *(float4*)(g + 256 + hb + 4) = make_float4(wq[4], wq[5], wq[6], wq[7]);
    }
  }

#pragma unroll
  for (int rep = 0; rep < 2; ++rep) {
    const int hp = l + rep * 64;
    const float p = (g[3 * hp] + g[3 * hp + 1] + g[3 * hp + 2]) * (1.0f / 96.0f);
    const float hs = b2f(feat16[(size_t)n * H + hp]);
    rst[(size_t)n * H + hp] = f2b(hs + p);
  }
}

// P1 = Wo_s@Wsc, P2 = Wo_c@Wcs (+ bf16 transposed copies), p1 = b_s@Wsc, p2 = b_c@Wcs
__global__ __launch_bounds__(128) void smallmm1(
    const void* __restrict__ Wos, const void* __restrict__ Woc,
    const void* __restrict__ Wsc, const void* __restrict__ Wcs,
    const void* __restrict__ bs, const void* __restrict__ bc,
    const int* __restrict__ flags,
    float* __restrict__ P1, float* __restrict__ P2,
    unsigned short* __restrict__ P1T, unsigned short* __restrict__ P2T,
    float* __restrict__ p1, float* __restrict__ p2)
{
  const int wf = flags[0];
  const int bid = blockIdx.x, c = threadIdx.x;
  if (bid < 128) {
    const int r = bid; float acc = 0.f;
    for (int k = 0; k < 128; ++k) acc += load1any(Wos, r * 128 + k, wf) * load1any(Wsc, k * 128 + c, wf);
    P1[r * 128 + c] = acc;
    P1T[c * 128 + r] = f2b(acc);
  } else if (bid < 256) {
    const int r = bid - 128; float acc = 0.f;
    for (int k = 0; k < 128; ++k) acc += load1any(Woc, r * 128 + k, wf) * load1any(Wcs, k * 128 + c, wf);
    P2[r * 128 + c] = acc;
    P2T[c * 128 + r] = f2b(acc);
  } else if (bid == 256) {
    float acc = 0.f;
    for (int k = 0; k < 128; ++k) acc += load1any(bs, k, wf) * load1any(Wsc, k * 128 + c, wf);
    p1[c] = acc;
  } else {
    float acc = 0.f;
    for (int k = 0; k < 128; ++k) acc += load1any(bc, k, wf) * load1any(Wcs, k * 128 + c, wf);
    p2[c] = acc;
  }
}

// MssT/MccT (bf16, transposed) + fused biases (f32)
__global__ __launch_bounds__(128) void smallmm2(
    const void* __restrict__ Wos, const void* __restrict__ Woc,
    const void* __restrict__ Wsc, const void* __restrict__ Wcs,
    const void* __restrict__ bs, const void* __restrict__ bc,
    const int* __restrict__ flags,
    const float* __restrict__ P1, const float* __restrict__ P2,
    const float* __restrict__ p1, const float* __restrict__ p2,
    unsigned short* __restrict__ MssT, unsigned short* __restrict__ MccT,
    float* __restrict__ bsim, float* __restrict__ bcor)
{
  const int wf = flags[0];
  const int bid = blockIdx.x, c = threadIdx.x;
  if (bid < 128) {
    const int r = bid; float acc = 0.f;
    for (int k = 0; k < 128; ++k) acc += P1[r * 128 + k] * load1any(Wcs, k * 128 + c, wf);
    MssT[c * 128 + r] = f2b(C_SELF * load1any(Wos, r * 128 + c, wf) + C_DBL * acc);
  } else if (bid < 256) {
    const int r = bid - 128; float acc = 0.f;
    for (int k = 0; k < 128; ++k) acc += P2[r * 128 + k] * load1any(Wsc, k * 128 + c, wf);
    MccT[c * 128 + r] = f2b(C_SELF * load1any(Woc, r * 128 + c, wf) + C_DBL * acc);
  } else if (bid == 256) {
    float acc = 0.f;
    for (int k = 0; k < 128; ++k) acc += p1[k] * load1any(Wcs, k * 128 + c, wf);
    bsim[c] = C_SELF * load1any(bs, c, wf) + C_CROSS * p2[c] + C_DBL * acc;
  } else {
    float acc = 0.f;
    for (int k = 0; k < 128; ++k) acc += p2[k] * load1any(Wsc, k * 128 + c, wf);
    bcor[c] = C_SELF * load1any(bc, c, wf) + C_CROSS * p1[c] + C_DBL * acc;
  }
}

// z2sim = Rs@Mss + C_CROSS*(Rc@P2) + bsim ; z2cor = Rc@Mcc + C_CROSS*(Rs@P1) + bcor
// MFMA version: B operands are transposed bf16 matrices. Block = 32 rows, 4 strip-waves.
__global__ __launch_bounds__(256) void finalmm_mfma(
    const unsigned short* __restrict__ Rs, const unsigned short* __restrict__ Rc,
    const unsigned short* __restrict__ MssT, const unsigned short* __restrict__ MccT,
    const unsigned short* __restrict__ P1T, const unsigned short* __restrict__ P2T,
    const float* __restrict__ bsim, const float* __restrict__ bcor,
    float* __restrict__ outp)
{
  const int t = threadIdx.x;
  const int w = t >> 6, l = t & 63, lane = l & 31, half = l >> 5;
  const int rbase = blockIdx.x * 32;
  const int arow = rbase + lane;
  const int n = w * 32 + lane;     // output column this lane owns

  const unsigned short* rsrow = Rs + (size_t)arow * H + half * 8;
  const unsigned short* rcrow = Rc + (size_t)arow * H + half * 8;
  bf16x8 aS[8], aC[8];
#pragma unroll
  for (int s = 0; s < 8; ++s) {
    aS[s] = *(const bf16x8*)(rsrow + s * 16);
    aC[s] = *(const bf16x8*)(rcrow + s * 16);
  }

  const unsigned short* bMss = MssT + (size_t)n * 128 + half * 8;
  const unsigned short* bMcc = MccT + (size_t)n * 128 + half * 8;
  const unsigned short* bP1  = P1T  + (size_t)n * 128 + half * 8;
  const unsigned short* bP2  = P2T  + (size_t)n * 128 + half * 8;

  f32x16 a1 = {0,0,0,0,0,0,0,0,0,0,0,0,0,0,0,0};   // Rs@Mss
  f32x16 a2 = a1, a3 = a1, a4 = a1;                 // Rc@P2, Rc@Mcc, Rs@P1
#pragma unroll
  for (int s = 0; s < 8; ++s) {
    bf16x8 b1 = *(const bf16x8*)(bMss + s * 16);
    bf16x8 b2 = *(const bf16x8*)(bP2  + s * 16);
    bf16x8 b3 = *(const bf16x8*)(bMcc + s * 16);
    bf16x8 b4 = *(const bf16x8*)(bP1  + s * 16);
    a1 = __builtin_amdgcn_mfma_f32_32x32x16_bf16(aS[s], b1, a1, 0, 0, 0);
    a2 = __builtin_amdgcn_mfma_f32_32x32x16_bf16(aC[s], b2, a2, 0, 0, 0);
    a3 = __builtin_amdgcn_mfma_f32_32x32x16_bf16(aC[s], b3, a3, 0, 0, 0);
    a4 = __builtin_amdgcn_mfma_f32_32x32x16_bf16(aS[s], b4, a4, 0, 0, 0);
  }

  const float bsv = bsim[n], bcv = bcor[n];
#pragma unroll
  for (int i = 0; i < 16; ++i) {
    const int m = (i & 3) + 8 * (i >> 2) + 4 * half;
    const int row = rbase + m;
    outp[(size_t)row * H + n] = a1[i] + C_CROSS * a2[i] + bsv;
    outp[(size_t)NDST * H + (size_t)row * H + n] = a3[i] + C_CROSS * a4[i] + bcv;
  }
}

extern "C" void kernel_launch(void* const* d_in, const int* in_sizes, int n_in,
                              void* d_out, int out_size, void* d_ws, size_t ws_size,
                              hipStream_t stream) {
  const int* x    = (const int*)d_in[0];
  const int* nsim = (const int*)d_in[1];
  const int* ncor = (const int*)d_in[2];
  const void* emb0_sim = d_in[3];
  const void* emb1_sim = d_in[4];
  const void* emb0_cor = d_in[5];
  const void* emb1_cor = d_in[6];
  const void* W_in_sim  = d_in[7];
  const void* b_in_sim  = d_in[8];
  const void* W_in_cor  = d_in[9];
  const void* b_in_cor  = d_in[10];
  const void* W_out_sim = d_in[11];
  const void* b_out_sim = d_in[12];
  const void* W_out_cor = d_in[13];
  const void* b_out_cor = d_in[14];
  const void* W_sim2cor = d_in[15];
  const void* W_cor2sim = d_in[16];

  // layout: f32 smalls | flags | bf16 tables | rst | fp8 tables | WT | transposed bf16
  float* fbase = (float*)d_ws;
  float* P1  = fbase;                   // 128*128 f32 each
  float* P2  = P1 + H * H;
  float* p1v = P2 + H * H;              // 128 f32 each
  float* p2v = p1v + H;
  float* bsimv = p2v + H;
  float* bcorv = bsimv + H;
  int* flags = (int*)(bcorv + H);       // 4 ints
  unsigned short* feat16_sim = (unsigned short*)(flags + 4);     // NDST*H
  unsigned short* feat16_cor = feat16_sim + (size_t)NDST * H;
  unsigned short* rst_sim    = feat16_cor + (size_t)NDST * H;    // NDST*H
  unsigned short* rst_cor    = rst_sim + (size_t)NDST * H;
  unsigned char* feat8_sim = (unsigned char*)(rst_cor + (size_t)NDST * H);  // NSRC*H bytes
  unsigned char* feat8_cor = feat8_sim + (size_t)NSRC * H;
  unsigned short* WT_sim = (unsigned short*)(feat8_cor + (size_t)NSRC * H); // 128*128 bf16 each
  unsigned short* WT_cor = WT_sim + H * H;
  unsigned short* P1T  = WT_cor + H * H;
  unsigned short* P2T  = P1T + H * H;
  unsigned short* MssT = P2T + H * H;
  unsigned short* MccT = MssT + H * H;

  detect<<<1, 64, 0, stream>>>((const unsigned short*)W_in_sim, x, flags);
  wprep<<<256, 128, 0, stream>>>(W_in_sim, W_in_cor, flags, WT_sim, WT_cor);
  smallmm1<<<258, 128, 0, stream>>>(W_out_sim, W_out_cor, W_sim2cor, W_cor2sim,
                                    b_out_sim, b_out_cor, flags, P1, P2, P1T, P2T, p1v, p2v);
  smallmm2<<<258, 128, 0, stream>>>(W_out_sim, W_out_cor, W_sim2cor, W_cor2sim,
                                    b_out_sim, b_out_cor, flags, P1, P2, p1v, p2v,
                                    MssT, MccT, bsimv, bcorv);
  featgemm_mfma<<<NSRC / 128, 256, 0, stream>>>(x, emb0_sim, emb1_sim, WT_sim, b_in_sim,
                                                flags, feat8_sim, feat16_sim);
  featgemm_mfma<<<NSRC / 128, 256, 0, stream>>>(x, emb0_cor, emb1_cor, WT_cor, b_in_cor,
                                                flags, feat8_cor, feat16_cor);
  // mode 'sim': D = feat[neigh_cor], Q = feat[neigh_sim]
  coatt_mfma<<<NDST / 4, 256, 0, stream>>>(feat8_sim, feat16_sim, ncor, nsim, rst_sim);
  // mode 'cor': D = feat[neigh_sim], Q = feat[neigh_cor]
  coatt_mfma<<<NDST / 4, 256, 0, stream>>>(feat8_cor, feat16_cor, nsim, ncor, rst_cor);
  finalmm_mfma<<<NDST / 32, 256, 0, stream>>>(rst_sim, rst_cor, MssT, MccT, P1T, P2T,
                                              bsimv, bcorv, (float*)d_out);
}